// Round 2
// baseline (235.229 us; speedup 1.0000x reference)
//
#include <hip/hip_runtime.h>

#define B_SZ   8
#define S_LEN  4096
#define D_K    128
#define KB     64      // keys per step
#define CH     13      // steps per chunk; sum over tiles of ceil((2q+2)/13) * 8 batches == 768 exactly
#define NCHUNK 768

// LDS strides in shorts (padded; read/write bank patterns verified conflict-optimal)
#define KT_STR 136
#define VT_STR 72
#define PT_STR 72

typedef short  short8  __attribute__((ext_vector_type(8)));
typedef float  floatx4 __attribute__((ext_vector_type(4)));

#define EXP2F(x) exp2f(x)
#define NCH(q) ((2*(q) + 14) / 13)   // ceil((2q+2)/13)

__device__ __forceinline__ unsigned bfround(float x) {
  unsigned u = __builtin_bit_cast(unsigned, x);
  return (u + 0x7fffu + ((u >> 16) & 1u)) >> 16;
}
__device__ __forceinline__ unsigned bfpack2(float a, float b) {
  return bfround(a) | (bfround(b) << 16);
}
// single-instruction RTNE pack (hot loop only)
__device__ __forceinline__ unsigned cvtpk(float lo, float hi) {
  unsigned r;
  asm("v_cvt_pk_bf16_f32 %0, %1, %2" : "=v"(r) : "v"(lo), "v"(hi));
  return r;
}

// ======================= pre-pass: fused K-convert + V-transpose =======================
// grid 1024 x 256. Each block: converts 4096 floats of K to bf16, and transposes one
// 64x64 tile of V into Vt[d][k] bf16.

__global__ __launch_bounds__(256)
void prep(const float* __restrict__ K, const float* __restrict__ V,
          unsigned short* __restrict__ Kb, unsigned short* __restrict__ Vt) {
  const int tid = threadIdx.x;
  const int bid = blockIdx.x;

  // ---- K convert ----
#pragma unroll
  for (int it = 0; it < 2; ++it) {
    const size_t idx = (size_t)bid * 4096 + it * 2048 + tid * 8;
    float4 f0 = *(const float4*)(K + idx);
    float4 f1 = *(const float4*)(K + idx + 4);
    uint4 u;
    u.x = bfpack2(f0.x, f0.y);
    u.y = bfpack2(f0.z, f0.w);
    u.z = bfpack2(f1.x, f1.y);
    u.w = bfpack2(f1.z, f1.w);
    *(uint4*)(Kb + idx) = u;
  }

  // ---- V transpose tile ----
  __shared__ float tile[64][65];
  const int vb  = bid >> 7;
  const int rem = bid & 127;
  const int ktt = (rem >> 1) * 64;
  const int dt  = (rem & 1) * 64;
  {
    const int c  = (tid & 15) * 4;
    const int r0 = tid >> 4;
#pragma unroll
    for (int rr2 = 0; rr2 < 4; ++rr2) {
      const int rr = r0 + rr2 * 16;
      float4 f = *(const float4*)(V + (size_t)(vb * S_LEN + ktt + rr) * D_K + dt + c);
      tile[rr][c]     = f.x;
      tile[rr][c + 1] = f.y;
      tile[rr][c + 2] = f.z;
      tile[rr][c + 3] = f.w;
    }
  }
  __syncthreads();
  {
    const int d  = tid >> 2;
    const int k0 = (tid & 3) * 16;
#pragma unroll
    for (int jj = 0; jj < 16; jj += 8) {
      uint4 u;
      u.x = bfpack2(tile[k0 + jj + 0][d], tile[k0 + jj + 1][d]);
      u.y = bfpack2(tile[k0 + jj + 2][d], tile[k0 + jj + 3][d]);
      u.z = bfpack2(tile[k0 + jj + 4][d], tile[k0 + jj + 5][d]);
      u.w = bfpack2(tile[k0 + jj + 6][d], tile[k0 + jj + 7][d]);
      *(uint4*)(Vt + (size_t)(vb * D_K + dt + d) * S_LEN + ktt + k0 + jj) = u;
    }
  }
}

// ======================= worker kernel =======================
// 256 threads (4 waves), 128-query tile per block; each wave owns 32 queries as two
// 16-q subtiles sharing K A-frag / V B-frag reads. Static schedule: block = chunk
// (b, tile q desc, chunk j), CH=13 key-steps max -> exactly 768 chunks.
// T14 async-stage: next step's K loads issued before QK^T, V loads after softmax;
// LDS written after the end-of-step barrier.
// __launch_bounds__(256,2): VGPR cap 256. (256,3) capped at ~170 and SPILLED the
// 32-float score tile to scratch (+260 MB HBM writes, R1 post-mortem) while still
// only achieving 2 blocks/CU. Working set is ~200 VGPRs; 2 is the honest bound.

__global__ __launch_bounds__(256, 2)
void attn_worker(const float* __restrict__ Q, const unsigned short* __restrict__ Kb,
                 const unsigned short* __restrict__ Vt,
                 float* __restrict__ ml, float* __restrict__ pO) {
  __shared__ __align__(16) short Klds[KB * KT_STR];      // 17408 B
  __shared__ __align__(16) short Vtlds[D_K * VT_STR];    // 18432 B
  __shared__ __align__(16) short Plds[4 * 16 * PT_STR];  //  9216 B  (45056 total)

  const int tid  = threadIdx.x;
  const int lane = tid & 63;
  const int w    = tid >> 6;        // wave 0..3
  const int l15  = lane & 15;
  const int quad = lane >> 4;

  // ---- chunk decode: blockIdx -> (batch b, tile q descending, chunk j) ----
  const int cidx = blockIdx.x;
  const int b = cidx & 7;
  int q = 31, r = cidx >> 3;        // r in [0,96)
  while (r >= NCH(q)) { r -= NCH(q); --q; }
  const int j  = r;
  const int q0 = q * 128;
  const int s0 = j * CH;
  const int s1 = min(s0 + CH, 2 * q + 2);

  // staging decomposition (256 threads; 64B contiguous per thread => coalesced global,
  // conflict-optimal LDS writes: bank group (row + 4*chunk) mod 8 is balanced)
  const int kr  = tid >> 2;         // K row 0..63
  const int kc2 = (tid & 3) * 32;   // K col chunk (shorts)
  const int vr  = tid >> 1;         // Vt row 0..127
  const int vc2 = (tid & 1) * 32;   // Vt col chunk (shorts)

  const float CSC = 0.12752041f;    // log2(e)/sqrt(128)

  // ---- Q fragments for 2 subtiles (B-operand: n=l15=query, k=quad*8 offset = d) ----
  short8 bq[2][4];
  int qg[2];
#pragma unroll
  for (int sub = 0; sub < 2; ++sub) {
    qg[sub] = q0 + w * 32 + sub * 16 + l15;
    const float* qptr = Q + (size_t)(b * S_LEN + qg[sub]) * D_K + quad * 8;
#pragma unroll
    for (int kd = 0; kd < 4; ++kd) {
      float4 f0 = *(const float4*)(qptr + kd * 32);
      float4 f1 = *(const float4*)(qptr + kd * 32 + 4);
      union { short8 s; unsigned u[4]; } t;
      t.u[0] = cvtpk(f0.x, f0.y);
      t.u[1] = cvtpk(f0.z, f0.w);
      t.u[2] = cvtpk(f1.x, f1.y);
      t.u[3] = cvtpk(f1.z, f1.w);
      bq[sub][kd] = t.s;
    }
  }

  floatx4 acc[2][8];
#pragma unroll
  for (int sub = 0; sub < 2; ++sub)
#pragma unroll
    for (int nc = 0; nc < 8; ++nc) acc[sub][nc] = (floatx4){0.f, 0.f, 0.f, 0.f};
  float m_run[2] = {-1e30f, -1e30f}, l_run[2] = {0.f, 0.f};

  const unsigned short* kb0 = Kb + (size_t)b * S_LEN * D_K;
  const unsigned short* vb0 = Vt + (size_t)b * D_K * S_LEN;

  uint4 kpf[4], vpf[4];

  // ---- prologue: stage step s0 directly ----
  {
    const unsigned short* kp = kb0 + (size_t)(s0 * KB) * D_K;
    const unsigned short* vp = vb0 + s0 * KB;
#pragma unroll
    for (int i = 0; i < 4; ++i) kpf[i] = *(const uint4*)(kp + (size_t)kr * D_K + kc2 + i * 8);
#pragma unroll
    for (int i = 0; i < 4; ++i) vpf[i] = *(const uint4*)(vp + (size_t)vr * S_LEN + vc2 + i * 8);
#pragma unroll
    for (int i = 0; i < 4; ++i) *(uint4*)(&Klds[kr * KT_STR + kc2 + i * 8]) = kpf[i];
#pragma unroll
    for (int i = 0; i < 4; ++i) *(uint4*)(&Vtlds[vr * VT_STR + vc2 + i * 8]) = vpf[i];
  }
  __syncthreads();

  for (int s = s0; s < s1; ++s) {
    const int kt  = s * KB;
    const bool hn  = (s + 1 < s1);
    const bool act = (kt <= q0 + w * 32 + 31);   // wave fully masked beyond this

    // ---- prefetch next K (full-step latency cover) ----
    if (hn) {
      const unsigned short* kp = kb0 + (size_t)((s + 1) * KB) * D_K;
#pragma unroll
      for (int i = 0; i < 4; ++i) kpf[i] = *(const uint4*)(kp + (size_t)kr * D_K + kc2 + i * 8);
    }

    floatx4 st[2][4];
    short8 pa[2][2];
    if (act) {
      // ---- S^T = K*Q^T for both subtiles; each A-frag read used twice ----
#pragma unroll
      for (int kf = 0; kf < 4; ++kf) {
        floatx4 c0 = (floatx4){0.f, 0.f, 0.f, 0.f};
        floatx4 c1 = (floatx4){0.f, 0.f, 0.f, 0.f};
#pragma unroll
        for (int kd = 0; kd < 4; ++kd) {
          short8 a = *(const short8*)(&Klds[(kf * 16 + l15) * KT_STR + kd * 32 + quad * 8]);
          c0 = __builtin_amdgcn_mfma_f32_16x16x32_bf16(a, bq[0][kd], c0, 0, 0, 0);
          c1 = __builtin_amdgcn_mfma_f32_16x16x32_bf16(a, bq[1][kd], c1, 0, 0, 0);
        }
        st[0][kf] = c0;
        st[1][kf] = c1;
      }

      // ---- causal mask (boundary steps only) ----
#pragma unroll
      for (int sub = 0; sub < 2; ++sub) {
        if (kt + 63 > q0 + w * 32 + sub * 16) {
#pragma unroll
          for (int kf = 0; kf < 4; ++kf)
#pragma unroll
            for (int rr = 0; rr < 4; ++rr) {
              int key = kt + kf * 16 + quad * 4 + rr;
              if (key > qg[sub]) st[sub][kf][rr] = -1e30f;
            }
        }
      }

      // ---- online softmax + P roundtrip + (guarded) rescale, per subtile ----
#pragma unroll
      for (int sub = 0; sub < 2; ++sub) {
        float mx = st[sub][0][0];
#pragma unroll
        for (int kf = 0; kf < 4; ++kf)
#pragma unroll
          for (int rr = 0; rr < 4; ++rr) mx = fmaxf(mx, st[sub][kf][rr]);
        mx = fmaxf(mx, __shfl_xor(mx, 16, 64));
        mx = fmaxf(mx, __shfl_xor(mx, 32, 64));
        const float m_new = fmaxf(m_run[sub], mx);
        const bool  grow  = __any(m_new > m_run[sub]);
        const float alpha = grow ? EXP2F((m_run[sub] - m_new) * CSC) : 1.0f;

        float p[4][4];
        float tsum = 0.f;
#pragma unroll
        for (int kf = 0; kf < 4; ++kf)
#pragma unroll
          for (int rr = 0; rr < 4; ++rr) {
            p[kf][rr] = EXP2F((st[sub][kf][rr] - m_new) * CSC);
            tsum += p[kf][rr];
          }
        tsum += __shfl_xor(tsum, 16, 64);
        tsum += __shfl_xor(tsum, 32, 64);
        l_run[sub] = l_run[sub] * alpha + tsum;
        m_run[sub] = m_new;

        if (grow) {
#pragma unroll
          for (int rr = 0; rr < 4; ++rr) {
            const float ar = __shfl(alpha, quad * 4 + rr, 64);
#pragma unroll
            for (int nc = 0; nc < 8; ++nc) acc[sub][nc][rr] *= ar;
          }
        }

        // P: C-layout -> A-layout via wave-private LDS rows (in-order per wave)
        short* pw = &Plds[(w * 16 + l15) * PT_STR];
#pragma unroll
        for (int kf = 0; kf < 4; ++kf) {
          uint2 u;
          u.x = cvtpk(p[kf][0], p[kf][1]);
          u.y = cvtpk(p[kf][2], p[kf][3]);
          *(uint2*)(&pw[kf * 16 + quad * 4]) = u;
        }
        __asm__ __volatile__("" ::: "memory");
        pa[sub][0] = *(const short8*)(&pw[quad * 8]);
        pa[sub][1] = *(const short8*)(&pw[32 + quad * 8]);
        __asm__ __volatile__("" ::: "memory");
      }
    }

    // ---- prefetch next V (covered by PV) ----
    if (hn) {
      const unsigned short* vp = vb0 + (s + 1) * KB;
#pragma unroll
      for (int i = 0; i < 4; ++i) vpf[i] = *(const uint4*)(vp + (size_t)vr * S_LEN + vc2 + i * 8);
    }

    if (act) {
      // ---- O += P*V ; each B-frag read used by both subtiles ----
#pragma unroll
      for (int nc = 0; nc < 8; ++nc) {
        short8 bv0 = *(const short8*)(&Vtlds[(nc * 16 + l15) * VT_STR + quad * 8]);
        short8 bv1 = *(const short8*)(&Vtlds[(nc * 16 + l15) * VT_STR + 32 + quad * 8]);
        acc[0][nc] = __builtin_amdgcn_mfma_f32_16x16x32_bf16(pa[0][0], bv0, acc[0][nc], 0, 0, 0);
        acc[0][nc] = __builtin_amdgcn_mfma_f32_16x16x32_bf16(pa[0][1], bv1, acc[0][nc], 0, 0, 0);
        acc[1][nc] = __builtin_amdgcn_mfma_f32_16x16x32_bf16(pa[1][0], bv0, acc[1][nc], 0, 0, 0);
        acc[1][nc] = __builtin_amdgcn_mfma_f32_16x16x32_bf16(pa[1][1], bv1, acc[1][nc], 0, 0, 0);
      }
    }

    __syncthreads();                 // all reads of LDS(s) done
    if (hn) {
#pragma unroll
      for (int i = 0; i < 4; ++i) *(uint4*)(&Klds[kr * KT_STR + kc2 + i * 8]) = kpf[i];
#pragma unroll
      for (int i = 0; i < 4; ++i) *(uint4*)(&Vtlds[vr * VT_STR + vc2 + i * 8]) = vpf[i];
      __syncthreads();               // LDS(s+1) visible
    }
  }

  // ---- partial epilogue: unnormalized O + (m,l) ----
  const int slot = cidx;
  float* po = pO + (size_t)slot * 16384;
#pragma unroll
  for (int sub = 0; sub < 2; ++sub) {
#pragma unroll
    for (int rr = 0; rr < 4; ++rr) {
      const int qrow = w * 32 + sub * 16 + quad * 4 + rr;
      float* op = po + qrow * D_K + l15;
#pragma unroll
      for (int nc = 0; nc < 8; ++nc) op[nc * 16] = acc[sub][nc][rr];
    }
    if (quad == 0) {
      const int qrow = w * 32 + sub * 16 + l15;
      ml[(size_t)slot * 256 + qrow * 2]     = m_run[sub];
      ml[(size_t)slot * 256 + qrow * 2 + 1] = l_run[sub];
    }
  }
}

// ======================= combine kernel =======================
// 256 blocks (one per (b, q-tile)); rescale-and-sum up to 5 partials, normalize.

__global__ __launch_bounds__(256)
void attn_combine(const float* __restrict__ ml, const float* __restrict__ pO,
                  float* __restrict__ O) {
  const int t = blockIdx.x;           // 0..255
  const int b = t & 7;
  const int q = t >> 3;
  int D = 0;
  for (int tq = 31; tq > q; --tq) D += NCH(tq);
  const int ncb = NCH(q);             // 1..5
  const float CSC = 0.12752041f;

  const int tid = threadIdx.x;
  const int ql  = tid >> 1;           // 0..127
  const int dh  = (tid & 1) * 64;     // d-span of 64 floats

  float m[5], l[5], wgt[5];
  float M = -1e30f;
#pragma unroll
  for (int jj = 0; jj < 5; ++jj) {
    if (jj < ncb) {
      const size_t slot = (size_t)(D + jj) * 8 + b;
      m[jj] = ml[slot * 256 + ql * 2];
      l[jj] = ml[slot * 256 + ql * 2 + 1];
      M = fmaxf(M, m[jj]);
    }
  }
  float L = 0.f;
#pragma unroll
  for (int jj = 0; jj < 5; ++jj)
    if (jj < ncb) { wgt[jj] = EXP2F((m[jj] - M) * CSC); L += wgt[jj] * l[jj]; }
  const float inv = 1.0f / L;

  float4 out[16];
#pragma unroll
  for (int v = 0; v < 16; ++v) out[v] = make_float4(0.f, 0.f, 0.f, 0.f);
#pragma unroll
  for (int jj = 0; jj < 5; ++jj) {
    if (jj < ncb) {
      const size_t slot = (size_t)(D + jj) * 8 + b;
      const float* src = pO + slot * 16384 + ql * D_K + dh;
      const float wj = wgt[jj];
#pragma unroll
      for (int v = 0; v < 16; ++v) {
        float4 f = *(const float4*)(src + v * 4);
        out[v].x += wj * f.x;  out[v].y += wj * f.y;
        out[v].z += wj * f.z;  out[v].w += wj * f.w;
      }
    }
  }
  float* dst = O + ((size_t)(b * S_LEN) + q * 128 + ql) * D_K + dh;
#pragma unroll
  for (int v = 0; v < 16; ++v) {
    *(float4*)(dst + v * 4) = make_float4(out[v].x * inv, out[v].y * inv,
                                          out[v].z * inv, out[v].w * inv);
  }
}

// ======================= fallback (R2 kernel, known-good) =======================

__global__ __launch_bounds__(256, 2)
void attn_fwd_fb(const float* __restrict__ Q, const float* __restrict__ K,
                 const float* __restrict__ V, float* __restrict__ O) {
  __shared__ __align__(16) short Klds[KB * KT_STR];
  __shared__ __align__(16) short Vtlds[D_K * VT_STR];
  __shared__ __align__(16) short Plds[4 * 16 * PT_STR];

  const int tid  = threadIdx.x;
  const int lane = tid & 63;
  const int w    = tid >> 6;
  const int l15  = lane & 15;
  const int quad = lane >> 4;

  const int bid = blockIdx.x;
  const int b   = bid & 7;
  const int qi  = 63 - (bid >> 3);
  const int q0  = qi * 64;

  const float CSC = 0.12752041f;

  const int    qg   = q0 + w * 16 + l15;
  const float* qrow = Q + (size_t)(b * S_LEN + qg) * D_K + quad * 8;
  short8 bq[4];
#pragma unroll
  for (int kd = 0; kd < 4; ++kd) {
    float4 f0 = *(const float4*)(qrow + kd * 32);
    float4 f1 = *(const float4*)(qrow + kd * 32 + 4);
    union { short8 s; unsigned u[4]; } t;
    t.u[0] = bfpack2(f0.x, f0.y);
    t.u[1] = bfpack2(f0.z, f0.w);
    t.u[2] = bfpack2(f1.x, f1.y);
    t.u[3] = bfpack2(f1.z, f1.w);
    bq[kd] = t.s;
  }

  floatx4 acc[8];
#pragma unroll
  for (int nc = 0; nc < 8; ++nc) acc[nc] = (floatx4){0.f, 0.f, 0.f, 0.f};
  float m_run = -1e30f, l_run = 0.f;

  const int d4 = tid & 31;
  const int kq = tid >> 5;
  const int nsteps = qi + 1;

  for (int s = 0; s < nsteps; ++s) {
    const int kt = s * KB;
#pragma unroll
    for (int r2 = 0; r2 < 2; ++r2) {
      const int row = r2 * 32 + kq * 4;
      const float* kp = K + (size_t)(b * S_LEN + kt + row) * D_K + d4 * 4;
      const float* vp = V + (size_t)(b * S_LEN + kt + row) * D_K + d4 * 4;
      float4 fk[4], fv[4];
#pragma unroll
      for (int i = 0; i < 4; ++i) {
        fk[i] = *(const float4*)(kp + i * D_K);
        fv[i] = *(const float4*)(vp + i * D_K);
      }
#pragma unroll
      for (int i = 0; i < 4; ++i) {
        uint2 u;
        u.x = bfpack2(fk[i].x, fk[i].y);
        u.y = bfpack2(fk[i].z, fk[i].w);
        *(uint2*)(&Klds[(row + i) * KT_STR + d4 * 4]) = u;
      }
#pragma unroll
      for (int c = 0; c < 4; ++c) {
        float e0 = ((const float*)&fv[0])[c];
        float e1 = ((const float*)&fv[1])[c];
        float e2 = ((const float*)&fv[2])[c];
        float e3 = ((const float*)&fv[3])[c];
        uint2 u;
        u.x = bfpack2(e0, e1);
        u.y = bfpack2(e2, e3);
        *(uint2*)(&Vtlds[(d4 * 4 + c) * VT_STR + row]) = u;
      }
    }
    __syncthreads();

    floatx4 st[4];
#pragma unroll
    for (int kf = 0; kf < 4; ++kf) {
      floatx4 c = (floatx4){0.f, 0.f, 0.f, 0.f};
#pragma unroll
      for (int kd = 0; kd < 4; ++kd) {
        short8 a = *(const short8*)(&Klds[(kf * 16 + l15) * KT_STR + kd * 32 + quad * 8]);
        c = __builtin_amdgcn_mfma_f32_16x16x32_bf16(a, bq[kd], c, 0, 0, 0);
      }
      st[kf] = c;
    }

    if (s == nsteps - 1) {
#pragma unroll
      for (int kf = 0; kf < 4; ++kf)
#pragma unroll
        for (int rr = 0; rr < 4; ++rr) {
          int key = kt + kf * 16 + quad * 4 + rr;
          if (key > qg) st[kf][rr] = -1e30f;
        }
    }

    float mx = st[0][0];
#pragma unroll
    for (int kf = 0; kf < 4; ++kf)
#pragma unroll
      for (int rr = 0; rr < 4; ++rr) mx = fmaxf(mx, st[kf][rr]);
    mx = fmaxf(mx, __shfl_xor(mx, 16, 64));
    mx = fmaxf(mx, __shfl_xor(mx, 32, 64));
    const float m_new = fmaxf(m_run, mx);
    const float alpha = EXP2F((m_run - m_new) * CSC);

    float p[4][4];
    float tsum = 0.f;
#pragma unroll
    for (int kf = 0; kf < 4; ++kf)
#pragma unroll
      for (int rr = 0; rr < 4; ++rr) {
        p[kf][rr] = EXP2F((st[kf][rr] - m_new) * CSC);
        tsum += p[kf][rr];
      }
    tsum += __shfl_xor(tsum, 16, 64);
    tsum += __shfl_xor(tsum, 32, 64);
    l_run = l_run * alpha + tsum;
    m_run = m_new;

#pragma unroll
    for (int rr = 0; rr < 4; ++rr) {
      const float ar = __shfl(alpha, quad * 4 + rr, 64);
#pragma unroll
      for (int nc = 0; nc < 8; ++nc) acc[nc][rr] *= ar;
    }

    short* pw = &Plds[(w * 16 + l15) * PT_STR];
#pragma unroll
    for (int kf = 0; kf < 4; ++kf) {
      uint2 u;
      u.x = bfpack2(p[kf][0], p[kf][1]);
      u.y = bfpack2(p[kf][2], p[kf][3]);
      *(uint2*)(&pw[kf * 16 + quad * 4]) = u;
    }
    __asm__ __volatile__("" ::: "memory");
    short8 pa0 = *(const short8*)(&pw[quad * 8]);
    short8 pa1 = *(const short8*)(&pw[32 + quad * 8]);

#pragma unroll
    for (int nc = 0; nc < 8; ++nc) {
      short8 bv0 = *(const short8*)(&Vtlds[(nc * 16 + l15) * VT_STR + quad * 8]);
      acc[nc] = __builtin_amdgcn_mfma_f32_16x16x32_bf16(pa0, bv0, acc[nc], 0, 0, 0);
      short8 bv1 = *(const short8*)(&Vtlds[(nc * 16 + l15) * VT_STR + 32 + quad * 8]);
      acc[nc] = __builtin_amdgcn_mfma_f32_16x16x32_bf16(pa1, bv1, acc[nc], 0, 0, 0);
    }
    __syncthreads();
  }

#pragma unroll
  for (int rr = 0; rr < 4; ++rr) {
    const float lr  = __shfl(l_run, quad * 4 + rr, 64);
    const float inv = 1.0f / lr;
    const int qout  = q0 + w * 16 + quad * 4 + rr;
    float* op = O + (size_t)(b * S_LEN + qout) * D_K + l15;
#pragma unroll
    for (int nc = 0; nc < 8; ++nc) op[nc * 16] = acc[nc][rr] * inv;
  }
}

// ======================= launch =======================

extern "C" void kernel_launch(void* const* d_in, const int* in_sizes, int n_in,
                              void* d_out, int out_size, void* d_ws, size_t ws_size,
                              hipStream_t stream) {
  const float* Q = (const float*)d_in[0];
  const float* K = (const float*)d_in[1];
  const float* V = (const float*)d_in[2];
  float* O = (float*)d_out;

  const size_t elems = (size_t)B_SZ * S_LEN * D_K;   // 4.19M

  // ws layout (bytes):
  //   0          : ml    [768 slots][128 q][m,l]      =    786,432
  //   786,432    : partO [768 slots][128 q][128 d]f32 = 50,331,648
  //   51,118,080 : Kb bf16                            =  8,388,608
  //   59,506,688 : Vt bf16                            =  8,388,608
  //   total ~67.9 MB
  const size_t off_ml = 0;
  const size_t off_po = (size_t)NCHUNK * 256 * 4;
  const size_t off_kb = off_po + (size_t)NCHUNK * 16384 * 4;
  const size_t off_vt = off_kb + elems * 2;
  const size_t need   = off_vt + elems * 2;

  if (ws_size >= need) {
    char* ws = (char*)d_ws;
    float*          mlp = (float*)(ws + off_ml);
    float*          po  = (float*)(ws + off_po);
    unsigned short* Kb  = (unsigned short*)(ws + off_kb);
    unsigned short* Vt  = (unsigned short*)(ws + off_vt);

    prep<<<dim3(1024), dim3(256), 0, stream>>>(K, V, Kb, Vt);
    attn_worker<<<dim3(NCHUNK), dim3(256), 0, stream>>>(Q, Kb, Vt, mlp, po);
    attn_combine<<<dim3(256), dim3(256), 0, stream>>>(mlp, po, O);
  } else {
    attn_fwd_fb<<<dim3(512), dim3(256), 0, stream>>>(Q, K, V, O);
  }
}

// Round 3
// 217.700 us; speedup vs baseline: 1.0805x; 1.0805x over previous
//
#include <hip/hip_runtime.h>

#define B_SZ   8
#define S_LEN  4096
#define D_K    128
#define KB     64      // keys per step
#define CH     16      // steps per chunk (split-K granularity)
#define NCHUNK 1280    // total chunks (800 full + 480 remainder) -- R0-proven schedule

#define PT_STR 72      // P-LDS row stride in shorts (R0-proven)

typedef short  short8  __attribute__((ext_vector_type(8)));
typedef float  floatx4 __attribute__((ext_vector_type(4)));

#define EXP2F(x) exp2f(x)

__device__ __forceinline__ unsigned bfround(float x) {
  unsigned u = __builtin_bit_cast(unsigned, x);
  return (u + 0x7fffu + ((u >> 16) & 1u)) >> 16;
}
__device__ __forceinline__ unsigned bfpack2(float a, float b) {
  return bfround(a) | (bfround(b) << 16);
}
// single-instruction RTNE pack (hot loop only; numerics validated R1/R2)
__device__ __forceinline__ unsigned cvtpk(float lo, float hi) {
  unsigned r;
  asm("v_cvt_pk_bf16_f32 %0, %1, %2" : "=v"(r) : "v"(lo), "v"(hi));
  return r;
}

// Async global->LDS DMA, 16B per lane (wave writes 1024B contiguous LDS).
// CK-style addrspace casts via integer (C-style ptr-AS casts are rejected by clang;
// int route always compiles; flat-shared low 32 bits == LDS offset on gfx9+).
__device__ __forceinline__ void dma16(const void* g, const void* l) {
  __builtin_amdgcn_global_load_lds(
      (__attribute__((address_space(1))) unsigned int*)(unsigned long long)g,
      (__attribute__((address_space(3))) unsigned int*)(unsigned int)(unsigned long long)l,
      16, 0, 0);
}

// ======================= pre-pass: tile-image builder =======================
// One block per (b, step s): emits K and V^T as 16KB LDS tile IMAGES with the
// XOR bank-swizzle baked in (byte ^= ((row&7)<<4) within each 256B/128B row),
// so the worker can DMA them linearly via global_load_lds (rule #21:
// linear DMA dest + pre-swizzled source + swizzled read).
//   K image : [64 key-rows][128 bf16 = 256B]   row r, logical byte o at o^((r&7)<<4)
//   Vt image: [128 d-rows ][ 64 bf16 = 128B]   row d, logical byte o at o^((d&7)<<4)

__global__ __launch_bounds__(256)
void prep(const float* __restrict__ K, const float* __restrict__ V,
          unsigned short* __restrict__ Kb, unsigned short* __restrict__ Vt) {
  __shared__ float tile[64][129];     // V staging for transpose (33KB)
  const int tid = threadIdx.x;
  const int bid = blockIdx.x;         // b*64 + s
  const int b   = bid >> 6;
  const int s   = bid & 63;
  const int kt  = s * 64;

  // ---- K tile image ----
  {
    const int r  = tid >> 2;          // key row 0..63
    const int cq = tid & 3;           // 32-float quarter
    const float* kp = K + (size_t)(b * S_LEN + kt + r) * D_K + cq * 32;
    unsigned short* kdst = Kb + (size_t)bid * 8192 + r * 128;
    const int xr = (r & 7) << 4;      // byte XOR
#pragma unroll
    for (int j = 0; j < 4; ++j) {     // 4 chunks of 8 floats -> 16B bf16
      float4 f0 = *(const float4*)(kp + j * 8);
      float4 f1 = *(const float4*)(kp + j * 8 + 4);
      uint4 u;
      u.x = bfpack2(f0.x, f0.y);
      u.y = bfpack2(f0.z, f0.w);
      u.z = bfpack2(f1.x, f1.y);
      u.w = bfpack2(f1.z, f1.w);
      const int o = (cq * 64 + j * 16) ^ xr;
      *(uint4*)(kdst + (o >> 1)) = u;
    }
  }

  // ---- V tile: load to LDS f32 ----
  {
    const int k  = tid >> 2;
    const int cq = tid & 3;
    const float* vp = V + (size_t)(b * S_LEN + kt + k) * D_K + cq * 32;
#pragma unroll
    for (int i = 0; i < 8; ++i) {
      float4 f = *(const float4*)(vp + i * 4);
      tile[k][cq * 32 + i * 4]     = f.x;
      tile[k][cq * 32 + i * 4 + 1] = f.y;
      tile[k][cq * 32 + i * 4 + 2] = f.z;
      tile[k][cq * 32 + i * 4 + 3] = f.w;
    }
  }
  __syncthreads();

  // ---- V^T tile image (transposed + swizzled) ----
  {
    const int d = tid >> 1;           // d-row 0..127
    const int h = tid & 1;            // key half
    unsigned short* vdst = Vt + (size_t)bid * 8192 + d * 64;
    const int xr = (d & 7) << 4;
#pragma unroll
    for (int j = 0; j < 4; ++j) {     // 4 chunks of 8 keys -> 16B bf16
      const int k0 = h * 32 + j * 8;
      uint4 u;
      u.x = bfpack2(tile[k0 + 0][d], tile[k0 + 1][d]);
      u.y = bfpack2(tile[k0 + 2][d], tile[k0 + 3][d]);
      u.z = bfpack2(tile[k0 + 4][d], tile[k0 + 5][d]);
      u.w = bfpack2(tile[k0 + 6][d], tile[k0 + 7][d]);
      const int o = (h * 64 + j * 16) ^ xr;
      *(uint4*)(vdst + (o >> 1)) = u;
    }
  }
}

__global__ void zero_cnt(int* cnt) { *cnt = 0; }

// ======================= worker kernel =======================
// R0-proven skeleton: 128 threads (2 waves), 64-q tiles, LPT atomic chunk
// scheduling, unnormalized partial O + (m,l). NEW vs R0: double-buffered
// global_load_lds staging pipeline (issue s+2's DMAs after the barrier that
// frees the buffer; counted vmcnt(16), never 0 in-loop; raw s_barrier so the
// compiler's __syncthreads vmcnt-drain can't kill the pipeline). LDS reads
// apply the XOR swizzle baked into the tile images by prep.
// LDS 70,148B -> 2 blocks/CU; latency hidden by the pipeline, not occupancy.

__global__ __launch_bounds__(128, 2)
void attn_worker(const float* __restrict__ Q, const unsigned short* __restrict__ Kb,
                 const unsigned short* __restrict__ Vt, int* __restrict__ cnt,
                 float* __restrict__ ml, float* __restrict__ pO) {
  __shared__ __align__(16) short Klds[2][8192];          // 2 x 16KB
  __shared__ __align__(16) short Vtlds[2][8192];         // 2 x 16KB
  __shared__ __align__(16) short Plds[2 * 16 * PT_STR];  // 4608B
  __shared__ int s_chunk;

  const int tid  = threadIdx.x;
  const int lane = tid & 63;
  const int w    = tid >> 6;        // wave 0..1
  const int l15  = lane & 15;
  const int quad = lane >> 4;
  const int xk   = (l15 & 7) << 3;  // short-index XOR for swizzled reads

  const float CSC = 0.12752041f;    // log2(e)/sqrt(128)

  for (;;) {
    if (tid == 0) s_chunk = atomicAdd(cnt, 1);
    __syncthreads();
    const int c = s_chunk;
    if (c >= NCHUNK) break;

    // ---- closed-form decode, chunks enumerated in descending size (R0) ----
    int b, qi, j;
    if (c < 800) {                      // full 16-step chunks
      const int r = c >> 3;  b = c & 7;
      if      (r <  4) { qi = 63;               j = r;            }
      else if (r < 52) { qi = 62 - (r-4)/3;     j = (r-4)%3;      }
      else if (r < 84) { qi = 46 - (r-52)/2;    j = (r-52)%2;     }
      else             { qi = 30 - (r-84);      j = 0;            }
    } else {                            // remainder chunks, size 15..1
      const int rc = c - 800;
      const int s  = 15 - (rc >> 5);
      const int t  = rc & 31;
      b  = t & 7;
      qi = s - 1 + 16 * (t >> 3);
      j  = (qi + 1) >> 4;
    }

    const int q0 = qi * 64;
    const int s0 = j * CH;
    const int s1 = min(s0 + CH, qi + 1);

    // ---- Q fragments for 2 subtiles (B-operand: n=l15=query, k=quad*8+j=d) ----
    short8 bq[2][4];
    int qg[2];
#pragma unroll
    for (int sub = 0; sub < 2; ++sub) {
      qg[sub] = q0 + w * 32 + sub * 16 + l15;
      const float* qrow = Q + (size_t)(b * S_LEN + qg[sub]) * D_K + quad * 8;
#pragma unroll
      for (int kd = 0; kd < 4; ++kd) {
        float4 f0 = *(const float4*)(qrow + kd * 32);
        float4 f1 = *(const float4*)(qrow + kd * 32 + 4);
        union { short8 s; unsigned u[4]; } t;
        t.u[0] = bfpack2(f0.x, f0.y);
        t.u[1] = bfpack2(f0.z, f0.w);
        t.u[2] = bfpack2(f1.x, f1.y);
        t.u[3] = bfpack2(f1.z, f1.w);
        bq[sub][kd] = t.s;
      }
    }

    floatx4 acc[2][8];
#pragma unroll
    for (int sub = 0; sub < 2; ++sub)
#pragma unroll
      for (int nc = 0; nc < 8; ++nc) acc[sub][nc] = (floatx4){0.f, 0.f, 0.f, 0.f};
    float m_run[2] = {-1e30f, -1e30f}, l_run[2] = {0.f, 0.f};

    const unsigned short* kb0 = Kb + (size_t)b * 64 * 8192;   // tile images
    const unsigned short* vb0 = Vt + (size_t)b * 64 * 8192;
    const int lo = lane * 8;            // lane*16B in shorts

    // stage(buf, step): each wave DMAs its half (8KB K + 8KB V) = 16 instrs
#define STAGE(BUF, S)                                                          \
    do {                                                                       \
      const unsigned short* kg_ = kb0 + (size_t)(S) * 8192 + w * 4096 + lo;    \
      const unsigned short* vg_ = vb0 + (size_t)(S) * 8192 + w * 4096 + lo;    \
      short* kl_ = &Klds[BUF][w * 4096];                                       \
      short* vl_ = &Vtlds[BUF][w * 4096];                                      \
      _Pragma("unroll")                                                        \
      for (int i_ = 0; i_ < 8; ++i_) dma16(kg_ + i_ * 512, kl_ + i_ * 512);    \
      _Pragma("unroll")                                                        \
      for (int i_ = 0; i_ < 8; ++i_) dma16(vg_ + i_ * 512, vl_ + i_ * 512);    \
    } while (0)

    // ---- prologue: stage s0 (and s0+1 into the other buffer) ----
    STAGE(s0 & 1, s0);
    if (s0 + 1 < s1) {
      STAGE((s0 + 1) & 1, s0 + 1);
      asm volatile("s_waitcnt vmcnt(16)" ::: "memory");   // s0's 16 done
    } else {
      asm volatile("s_waitcnt vmcnt(0)" ::: "memory");
    }
    __builtin_amdgcn_s_barrier();
    __builtin_amdgcn_sched_barrier(0);

    for (int s = s0; s < s1; ++s) {
      const int kt  = s * KB;
      const int cur = s & 1;
      const short* Kl = &Klds[cur][0];
      const short* Vl = &Vtlds[cur][0];

      // ---- S^T = K*Q^T for both subtiles; each A-frag read used twice ----
      floatx4 st[2][4];
#pragma unroll
      for (int kf = 0; kf < 4; ++kf) {
        floatx4 c0 = (floatx4){0.f, 0.f, 0.f, 0.f};
        floatx4 c1 = (floatx4){0.f, 0.f, 0.f, 0.f};
#pragma unroll
        for (int kd = 0; kd < 4; ++kd) {
          short8 a = *(const short8*)(&Kl[((kf * 16 + l15) << 7) + ((kd * 32 + quad * 8) ^ xk)]);
          c0 = __builtin_amdgcn_mfma_f32_16x16x32_bf16(a, bq[0][kd], c0, 0, 0, 0);
          c1 = __builtin_amdgcn_mfma_f32_16x16x32_bf16(a, bq[1][kd], c1, 0, 0, 0);
        }
        st[0][kf] = c0;
        st[1][kf] = c1;
      }

      // ---- causal mask (diagonal step only) ----
      if (s == qi) {
#pragma unroll
        for (int sub = 0; sub < 2; ++sub)
#pragma unroll
          for (int kf = 0; kf < 4; ++kf)
#pragma unroll
            for (int r = 0; r < 4; ++r) {
              int key = kt + kf * 16 + quad * 4 + r;
              if (key > qg[sub]) st[sub][kf][r] = -1e30f;
            }
      }

      // ---- online softmax + P roundtrip + rescale, per subtile (R0) ----
      short8 pa[2][2];
#pragma unroll
      for (int sub = 0; sub < 2; ++sub) {
        float mx = st[sub][0][0];
#pragma unroll
        for (int kf = 0; kf < 4; ++kf)
#pragma unroll
          for (int r = 0; r < 4; ++r) mx = fmaxf(mx, st[sub][kf][r]);
        mx = fmaxf(mx, __shfl_xor(mx, 16, 64));
        mx = fmaxf(mx, __shfl_xor(mx, 32, 64));
        const float m_new = fmaxf(m_run[sub], mx);
        const float alpha = EXP2F((m_run[sub] - m_new) * CSC);

        float p[4][4];
        float tsum = 0.f;
#pragma unroll
        for (int kf = 0; kf < 4; ++kf)
#pragma unroll
          for (int r = 0; r < 4; ++r) {
            p[kf][r] = EXP2F((st[sub][kf][r] - m_new) * CSC);
            tsum += p[kf][r];
          }
        tsum += __shfl_xor(tsum, 16, 64);
        tsum += __shfl_xor(tsum, 32, 64);
        l_run[sub] = l_run[sub] * alpha + tsum;
        m_run[sub] = m_new;

#pragma unroll
        for (int r = 0; r < 4; ++r) {
          const float ar = __shfl(alpha, quad * 4 + r, 64);
#pragma unroll
          for (int nc = 0; nc < 8; ++nc) acc[sub][nc][r] *= ar;
        }

        // P: C-layout -> A-layout; wave-private rows (in-order LDS per wave)
        short* pw = &Plds[(w * 16 + l15) * PT_STR];
#pragma unroll
        for (int kf = 0; kf < 4; ++kf) {
          uint2 u;
          u.x = cvtpk(p[kf][0], p[kf][1]);
          u.y = cvtpk(p[kf][2], p[kf][3]);
          *(uint2*)(&pw[kf * 16 + quad * 4]) = u;
        }
        __asm__ __volatile__("" ::: "memory");
        pa[sub][0] = *(const short8*)(&pw[quad * 8]);
        pa[sub][1] = *(const short8*)(&pw[32 + quad * 8]);
        __asm__ __volatile__("" ::: "memory");
      }

      // ---- O += P*V ; each B-frag read used by both subtiles ----
#pragma unroll
      for (int nc = 0; nc < 8; ++nc) {
        short8 bv0 = *(const short8*)(&Vl[((nc * 16 + l15) << 6) + ((quad * 8) ^ xk)]);
        short8 bv1 = *(const short8*)(&Vl[((nc * 16 + l15) << 6) + ((32 + quad * 8) ^ xk)]);
        acc[0][nc] = __builtin_amdgcn_mfma_f32_16x16x32_bf16(pa[0][0], bv0, acc[0][nc], 0, 0, 0);
        acc[0][nc] = __builtin_amdgcn_mfma_f32_16x16x32_bf16(pa[0][1], bv1, acc[0][nc], 0, 0, 0);
        acc[1][nc] = __builtin_amdgcn_mfma_f32_16x16x32_bf16(pa[1][0], bv0, acc[1][nc], 0, 0, 0);
        acc[1][nc] = __builtin_amdgcn_mfma_f32_16x16x32_bf16(pa[1][1], bv1, acc[1][nc], 0, 0, 0);
      }

      // ---- pipeline advance: free buf[cur], stage s+2 into it, await s+1 ----
      asm volatile("s_waitcnt lgkmcnt(0)" ::: "memory");
      __builtin_amdgcn_s_barrier();               // all waves done reading buf[cur]
      __builtin_amdgcn_sched_barrier(0);
      if (s + 2 < s1) {
        STAGE(cur, s + 2);
        asm volatile("s_waitcnt vmcnt(16)" ::: "memory");  // s+1's 16 done
      } else if (s + 1 < s1) {
        asm volatile("s_waitcnt vmcnt(0)" ::: "memory");
      }
      __builtin_amdgcn_s_barrier();               // buf[s+1 & 1] visible to all
      __builtin_amdgcn_sched_barrier(0);
    }
#undef STAGE

    // ---- partial epilogue: unnormalized O + (m,l) (R0 verbatim) ----
    const int slot = ((b << 6) | qi) * 4 + j;
    float* po = pO + (size_t)slot * 8192;
#pragma unroll
    for (int sub = 0; sub < 2; ++sub) {
#pragma unroll
      for (int r = 0; r < 4; ++r) {
        const int qrow = w * 32 + sub * 16 + quad * 4 + r;
        float* op = po + qrow * D_K + l15;
#pragma unroll
        for (int nc = 0; nc < 8; ++nc) op[nc * 16] = acc[sub][nc][r];
      }
      if (quad == 0) {
        const int qrow = w * 32 + sub * 16 + l15;
        ml[(size_t)slot * 128 + qrow * 2]     = m_run[sub];
        ml[(size_t)slot * 128 + qrow * 2 + 1] = l_run[sub];
      }
    }
  }
}

// ======================= combine kernel (R0 verbatim) =======================

__global__ __launch_bounds__(256)
void attn_combine(const float* __restrict__ ml, const float* __restrict__ pO,
                  float* __restrict__ O) {
  const int t   = blockIdx.x;        // tile = b*64 + qi
  const int b   = t >> 6;
  const int qi  = t & 63;
  const int ncb = ((qi + 1) + 15) >> 4;   // chunks for this tile (1..4)
  const float CSC = 0.12752041f;

  const int tid = threadIdx.x;
  const int q   = tid >> 2;          // 0..63
  const int dp  = (tid & 3) * 32;    // d-span of 32 floats

  float m[4], l[4];
  float M = -1e30f;
  for (int jj = 0; jj < ncb; ++jj) {
    const int slot = t * 4 + jj;
    m[jj] = ml[(size_t)slot * 128 + q * 2];
    l[jj] = ml[(size_t)slot * 128 + q * 2 + 1];
    M = fmaxf(M, m[jj]);
  }
  float wgt[4], L = 0.f;
  for (int jj = 0; jj < ncb; ++jj) {
    wgt[jj] = EXP2F((m[jj] - M) * CSC);
    L += wgt[jj] * l[jj];
  }
  const float inv = 1.0f / L;

  float4 out[8];
#pragma unroll
  for (int v = 0; v < 8; ++v) out[v] = make_float4(0.f, 0.f, 0.f, 0.f);
  for (int jj = 0; jj < ncb; ++jj) {
    const float* src = pO + (size_t)(t * 4 + jj) * 8192 + q * D_K + dp;
    const float wj = wgt[jj];
#pragma unroll
    for (int v = 0; v < 8; ++v) {
      float4 f = *(const float4*)(src + v * 4);
      out[v].x += wj * f.x;  out[v].y += wj * f.y;
      out[v].z += wj * f.z;  out[v].w += wj * f.w;
    }
  }
  float* dst = O + (size_t)(b * S_LEN + qi * 64 + q) * D_K + dp;
#pragma unroll
  for (int v = 0; v < 8; ++v) {
    float4 f = make_float4(out[v].x * inv, out[v].y * inv, out[v].z * inv, out[v].w * inv);
    *(float4*)(dst + v * 4) = f;
  }
}

// ======================= fallback (known-good, ws-too-small path) =======================

#define KT_STR 136
#define VT_STR 72

__global__ __launch_bounds__(256, 2)
void attn_fwd_fb(const float* __restrict__ Q, const float* __restrict__ K,
                 const float* __restrict__ V, float* __restrict__ O) {
  __shared__ __align__(16) short Klds[KB * KT_STR];
  __shared__ __align__(16) short Vtlds[D_K * VT_STR];
  __shared__ __align__(16) short Plds[4 * 16 * PT_STR];

  const int tid  = threadIdx.x;
  const int lane = tid & 63;
  const int w    = tid >> 6;
  const int l15  = lane & 15;
  const int quad = lane >> 4;

  const int bid = blockIdx.x;
  const int b   = bid & 7;
  const int qi  = 63 - (bid >> 3);
  const int q0  = qi * 64;

  const float CSC = 0.12752041f;

  const int    qg   = q0 + w * 16 + l15;
  const float* qrow = Q + (size_t)(b * S_LEN + qg) * D_K + quad * 8;
  short8 bq[4];
#pragma unroll
  for (int kd = 0; kd < 4; ++kd) {
    float4 f0 = *(const float4*)(qrow + kd * 32);
    float4 f1 = *(const float4*)(qrow + kd * 32 + 4);
    union { short8 s; unsigned u[4]; } t;
    t.u[0] = bfpack2(f0.x, f0.y);
    t.u[1] = bfpack2(f0.z, f0.w);
    t.u[2] = bfpack2(f1.x, f1.y);
    t.u[3] = bfpack2(f1.z, f1.w);
    bq[kd] = t.s;
  }

  floatx4 acc[8];
#pragma unroll
  for (int nc = 0; nc < 8; ++nc) acc[nc] = (floatx4){0.f, 0.f, 0.f, 0.f};
  float m_run = -1e30f, l_run = 0.f;

  const int d4 = tid & 31;
  const int kq = tid >> 5;
  const int nsteps = qi + 1;

  for (int s = 0; s < nsteps; ++s) {
    const int kt = s * KB;
#pragma unroll
    for (int r2 = 0; r2 < 2; ++r2) {
      const int row = r2 * 32 + kq * 4;
      const float* kp = K + (size_t)(b * S_LEN + kt + row) * D_K + d4 * 4;
      const float* vp = V + (size_t)(b * S_LEN + kt + row) * D_K + d4 * 4;
      float4 fk[4], fv[4];
#pragma unroll
      for (int i = 0; i < 4; ++i) {
        fk[i] = *(const float4*)(kp + i * D_K);
        fv[i] = *(const float4*)(vp + i * D_K);
      }
#pragma unroll
      for (int i = 0; i < 4; ++i) {
        uint2 u;
        u.x = bfpack2(fk[i].x, fk[i].y);
        u.y = bfpack2(fk[i].z, fk[i].w);
        *(uint2*)(&Klds[(row + i) * KT_STR + d4 * 4]) = u;
      }
#pragma unroll
      for (int c = 0; c < 4; ++c) {
        float e0 = ((const float*)&fv[0])[c];
        float e1 = ((const float*)&fv[1])[c];
        float e2 = ((const float*)&fv[2])[c];
        float e3 = ((const float*)&fv[3])[c];
        uint2 u;
        u.x = bfpack2(e0, e1);
        u.y = bfpack2(e2, e3);
        *(uint2*)(&Vtlds[(d4 * 4 + c) * VT_STR + row]) = u;
      }
    }
    __syncthreads();

    floatx4 st[4];
#pragma unroll
    for (int kf = 0; kf < 4; ++kf) {
      floatx4 c = (floatx4){0.f, 0.f, 0.f, 0.f};
#pragma unroll
      for (int kd = 0; kd < 4; ++kd) {
        short8 a = *(const short8*)(&Klds[(kf * 16 + l15) * KT_STR + kd * 32 + quad * 8]);
        c = __builtin_amdgcn_mfma_f32_16x16x32_bf16(a, bq[kd], c, 0, 0, 0);
      }
      st[kf] = c;
    }

    if (s == nsteps - 1) {
#pragma unroll
      for (int kf = 0; kf < 4; ++kf)
#pragma unroll
        for (int rr = 0; rr < 4; ++rr) {
          int key = kt + kf * 16 + quad * 4 + rr;
          if (key > qg) st[kf][rr] = -1e30f;
        }
    }

    float mx = st[0][0];
#pragma unroll
    for (int kf = 0; kf < 4; ++kf)
#pragma unroll
      for (int rr = 0; rr < 4; ++rr) mx = fmaxf(mx, st[kf][rr]);
    mx = fmaxf(mx, __shfl_xor(mx, 16, 64));
    mx = fmaxf(mx, __shfl_xor(mx, 32, 64));
    const float m_new = fmaxf(m_run, mx);
    const float alpha = EXP2F((m_run - m_new) * CSC);

    float p[4][4];
    float tsum = 0.f;
#pragma unroll
    for (int kf = 0; kf < 4; ++kf)
#pragma unroll
      for (int rr = 0; rr < 4; ++rr) {
        p[kf][rr] = EXP2F((st[kf][rr] - m_new) * CSC);
        tsum += p[kf][rr];
      }
    tsum += __shfl_xor(tsum, 16, 64);
    tsum += __shfl_xor(tsum, 32, 64);
    l_run = l_run * alpha + tsum;
    m_run = m_new;

#pragma unroll
    for (int rr = 0; rr < 4; ++rr) {
      const float ar = __shfl(alpha, quad * 4 + rr, 64);
#pragma unroll
      for (int nc = 0; nc < 8; ++nc) acc[nc][rr] *= ar;
    }

    short* pw = &Plds[(w * 16 + l15) * PT_STR];
#pragma unroll
    for (int kf = 0; kf < 4; ++kf) {
      uint2 u;
      u.x = bfpack2(p[kf][0], p[kf][1]);
      u.y = bfpack2(p[kf][2], p[kf][3]);
      *(uint2*)(&pw[kf * 16 + quad * 4]) = u;
    }
    __asm__ __volatile__("" ::: "memory");
    short8 pa0 = *(const short8*)(&pw[quad * 8]);
    short8 pa1 = *(const short8*)(&pw[32 + quad * 8]);

#pragma unroll
    for (int nc = 0; nc < 8; ++nc) {
      short8 bv0 = *(const short8*)(&Vtlds[(nc * 16 + l15) * VT_STR + quad * 8]);
      acc[nc] = __builtin_amdgcn_mfma_f32_16x16x32_bf16(pa0, bv0, acc[nc], 0, 0, 0);
      short8 bv1 = *(const short8*)(&Vtlds[(nc * 16 + l15) * VT_STR + 32 + quad * 8]);
      acc[nc] = __builtin_amdgcn_mfma_f32_16x16x32_bf16(pa1, bv1, acc[nc], 0, 0, 0);
    }
    __syncthreads();
  }

#pragma unroll
  for (int rr = 0; rr < 4; ++rr) {
    const float lr  = __shfl(l_run, quad * 4 + rr, 64);
    const float inv = 1.0f / lr;
    const int qout  = q0 + w * 16 + quad * 4 + rr;
    float* op = O + (size_t)(b * S_LEN + qout) * D_K + l15;
#pragma unroll
    for (int nc = 0; nc < 8; ++nc) op[nc * 16] = acc[nc][rr] * inv;
  }
}

// ======================= launch =======================

extern "C" void kernel_launch(void* const* d_in, const int* in_sizes, int n_in,
                              void* d_out, int out_size, void* d_ws, size_t ws_size,
                              hipStream_t stream) {
  const float* Q = (const float*)d_in[0];
  const float* K = (const float*)d_in[1];
  const float* V = (const float*)d_in[2];
  float* O = (float*)d_out;

  const size_t elems = (size_t)B_SZ * S_LEN * D_K;   // 4.19M

  // ws layout (bytes) -- R0 verbatim:
  //   0        : counter (int)
  //   256      : ml      [2048 slots][64 q][m,l]  = 1,048,576
  //   1,048,832: partO   [2048 slots][64][128]f32 = 67,108,864
  //   68,157,696: Kb tile-images bf16             =  8,388,608
  //   76,546,304: Vt tile-images bf16             =  8,388,608
  const size_t off_ml = 256;
  const size_t off_po = off_ml + 2048ull * 128 * 4;
  const size_t off_kb = off_po + 2048ull * 8192 * 4;
  const size_t off_vt = off_kb + elems * 2;
  const size_t need   = off_vt + elems * 2;

  if (ws_size >= need) {
    char* ws = (char*)d_ws;
    int*            cnt = (int*)ws;
    float*          mlp = (float*)(ws + off_ml);
    float*          po  = (float*)(ws + off_po);
    unsigned short* Kbp = (unsigned short*)(ws + off_kb);
    unsigned short* Vtp = (unsigned short*)(ws + off_vt);

    zero_cnt<<<dim3(1), dim3(1), 0, stream>>>(cnt);
    prep<<<dim3(B_SZ * 64), dim3(256), 0, stream>>>(K, V, Kbp, Vtp);
    attn_worker<<<dim3(1024), dim3(128), 0, stream>>>(Q, Kbp, Vtp, cnt, mlp, po);
    attn_combine<<<dim3(512), dim3(256), 0, stream>>>(mlp, po, O);
  } else {
    attn_fwd_fb<<<dim3(512), dim3(256), 0, stream>>>(Q, K, V, O);
  }
}

// Round 4
// 187.568 us; speedup vs baseline: 1.2541x; 1.1606x over previous
//
#include <hip/hip_runtime.h>

#define B_SZ   8
#define S_LEN  4096
#define D_K    128
#define KB     64      // keys per step
#define CH     16      // steps per chunk (split-K granularity)
#define NCHUNK 640     // 416 full 16-step chunks + 224 remainder chunks (128-q tiles)

#define PT_STR 72      // P-LDS row stride in shorts (R0-proven)

typedef short  short8  __attribute__((ext_vector_type(8)));
typedef float  floatx4 __attribute__((ext_vector_type(4)));

#define EXP2F(x) exp2f(x)

__device__ __forceinline__ unsigned bfround(float x) {
  unsigned u = __builtin_bit_cast(unsigned, x);
  return (u + 0x7fffu + ((u >> 16) & 1u)) >> 16;
}
__device__ __forceinline__ unsigned bfpack2(float a, float b) {
  return bfround(a) | (bfround(b) << 16);
}
// single-instruction RTNE pack (hot loop only; numerics validated R1-R3)
__device__ __forceinline__ unsigned cvtpk(float lo, float hi) {
  unsigned r;
  asm("v_cvt_pk_bf16_f32 %0, %1, %2" : "=v"(r) : "v"(lo), "v"(hi));
  return r;
}

// Async global->LDS DMA, 16B per lane (wave writes 1024B contiguous LDS).
__device__ __forceinline__ void dma16(const void* g, const void* l) {
  __builtin_amdgcn_global_load_lds(
      (__attribute__((address_space(1))) unsigned int*)(unsigned long long)g,
      (__attribute__((address_space(3))) unsigned int*)(unsigned int)(unsigned long long)l,
      16, 0, 0);
}

// ======================= pre-pass: tile-image builder (R3 verbatim) =======================
// One block per (b, step s): emits K and V^T as 16KB LDS tile IMAGES with the
// XOR bank-swizzle baked in (byte ^= ((row&7)<<4)), so the worker can DMA them
// linearly via global_load_lds (rule #21: linear dest + pre-swizzled source +
// swizzled read).

__global__ __launch_bounds__(256)
void prep(const float* __restrict__ K, const float* __restrict__ V,
          unsigned short* __restrict__ Kb, unsigned short* __restrict__ Vt) {
  __shared__ float tile[64][129];
  const int tid = threadIdx.x;
  const int bid = blockIdx.x;         // b*64 + s
  const int b   = bid >> 6;
  const int s   = bid & 63;
  const int kt  = s * 64;

  // ---- K tile image ----
  {
    const int r  = tid >> 2;
    const int cq = tid & 3;
    const float* kp = K + (size_t)(b * S_LEN + kt + r) * D_K + cq * 32;
    unsigned short* kdst = Kb + (size_t)bid * 8192 + r * 128;
    const int xr = (r & 7) << 4;
#pragma unroll
    for (int jj = 0; jj < 4; ++jj) {
      float4 f0 = *(const float4*)(kp + jj * 8);
      float4 f1 = *(const float4*)(kp + jj * 8 + 4);
      uint4 u;
      u.x = bfpack2(f0.x, f0.y);
      u.y = bfpack2(f0.z, f0.w);
      u.z = bfpack2(f1.x, f1.y);
      u.w = bfpack2(f1.z, f1.w);
      const int o = (cq * 64 + jj * 16) ^ xr;
      *(uint4*)(kdst + (o >> 1)) = u;
    }
  }

  // ---- V tile: load to LDS f32 ----
  {
    const int k  = tid >> 2;
    const int cq = tid & 3;
    const float* vp = V + (size_t)(b * S_LEN + kt + k) * D_K + cq * 32;
#pragma unroll
    for (int i = 0; i < 8; ++i) {
      float4 f = *(const float4*)(vp + i * 4);
      tile[k][cq * 32 + i * 4]     = f.x;
      tile[k][cq * 32 + i * 4 + 1] = f.y;
      tile[k][cq * 32 + i * 4 + 2] = f.z;
      tile[k][cq * 32 + i * 4 + 3] = f.w;
    }
  }
  __syncthreads();

  // ---- V^T tile image (transposed + swizzled) ----
  {
    const int d = tid >> 1;
    const int h = tid & 1;
    unsigned short* vdst = Vt + (size_t)bid * 8192 + d * 64;
    const int xr = (d & 7) << 4;
#pragma unroll
    for (int jj = 0; jj < 4; ++jj) {
      const int k0 = h * 32 + jj * 8;
      uint4 u;
      u.x = bfpack2(tile[k0 + 0][d], tile[k0 + 1][d]);
      u.y = bfpack2(tile[k0 + 2][d], tile[k0 + 3][d]);
      u.z = bfpack2(tile[k0 + 4][d], tile[k0 + 5][d]);
      u.w = bfpack2(tile[k0 + 6][d], tile[k0 + 7][d]);
      const int o = (h * 64 + jj * 16) ^ xr;
      *(uint4*)(vdst + (o >> 1)) = u;
    }
  }
}

__global__ void zero_cnt(int* cnt) { *cnt = 0; }

// ======================= worker kernel =======================
// R4: 4 waves (256 thr), 128-query tile — same per-wave state as R3 (2 subtiles,
// acc[2][8]) but 2x arithmetic intensity per staged tile: block-steps halve
// (16,640 -> 8,448), and 2 resident blocks/CU now carry 8 waves = 2 waves/SIMD
// (R0's TLP) WITH the R3 DMA double-buffer pipeline (counted vmcnt(8), raw
// s_barrier). LDS 74.8KB -> 2 blocks/CU. Atomic LPT over 640 chunks.

__global__ __launch_bounds__(256, 2)
void attn_worker(const float* __restrict__ Q, const unsigned short* __restrict__ Kb,
                 const unsigned short* __restrict__ Vt, int* __restrict__ cnt,
                 float* __restrict__ ml, float* __restrict__ pO) {
  __shared__ __align__(16) short Klds[2][8192];          // 2 x 16KB
  __shared__ __align__(16) short Vtlds[2][8192];         // 2 x 16KB
  __shared__ __align__(16) short Plds[4 * 16 * PT_STR];  // 9216B
  __shared__ int s_chunk;

  const int tid  = threadIdx.x;
  const int lane = tid & 63;
  const int w    = tid >> 6;        // wave 0..3
  const int l15  = lane & 15;
  const int quad = lane >> 4;
  const int xk   = (l15 & 7) << 3;  // short-index XOR for swizzled reads

  const float CSC = 0.12752041f;    // log2(e)/sqrt(128)

  for (;;) {
    if (tid == 0) s_chunk = atomicAdd(cnt, 1);
    __syncthreads();
    const int c = s_chunk;
    if (c >= NCHUNK) break;

    // ---- decode: 416 full chunks (desc q), then 224 remainders (desc size) ----
    int b, q, j;
    if (c < 416) {
      const int r = c >> 3;  b = c & 7;
      if      (r <  4) { q = 31;              j = r;         }
      else if (r < 28) { q = 30 - (r-4)/3;    j = (r-4)%3;   }
      else if (r < 44) { q = 22 - (r-28)/2;   j = (r-28)%2;  }
      else             { q = 14 - (r-44);     j = 0;         }
    } else {
      const int rc = c - 416;
      const int g  = rc >> 5;          // 0..6, remainder size 14-2g
      const int t  = rc & 31;
      b = t & 7;
      q = (6 - g) + 8 * (3 - (t >> 3));
      j = (q + 1) >> 3;                // = floor((2q+2)/16)
    }

    const int q0 = q * 128;
    const int s0 = j * CH;
    const int s1 = min(s0 + CH, 2 * q + 2);

    // ---- Q fragments for 2 subtiles (B-operand: n=l15=query, k=quad*8+i=d) ----
    short8 bq[2][4];
    int qg[2];
#pragma unroll
    for (int sub = 0; sub < 2; ++sub) {
      qg[sub] = q0 + w * 32 + sub * 16 + l15;
      const float* qrow = Q + (size_t)(b * S_LEN + qg[sub]) * D_K + quad * 8;
#pragma unroll
      for (int kd = 0; kd < 4; ++kd) {
        float4 f0 = *(const float4*)(qrow + kd * 32);
        float4 f1 = *(const float4*)(qrow + kd * 32 + 4);
        union { short8 s; unsigned u[4]; } t;
        t.u[0] = bfpack2(f0.x, f0.y);
        t.u[1] = bfpack2(f0.z, f0.w);
        t.u[2] = bfpack2(f1.x, f1.y);
        t.u[3] = bfpack2(f1.z, f1.w);
        bq[sub][kd] = t.s;
      }
    }

    floatx4 acc[2][8];
#pragma unroll
    for (int sub = 0; sub < 2; ++sub)
#pragma unroll
      for (int nc = 0; nc < 8; ++nc) acc[sub][nc] = (floatx4){0.f, 0.f, 0.f, 0.f};
    float m_run[2] = {-1e30f, -1e30f}, l_run[2] = {0.f, 0.f};

    const unsigned short* kb0 = Kb + (size_t)b * 64 * 8192;   // tile images
    const unsigned short* vb0 = Vt + (size_t)b * 64 * 8192;
    const int lo = lane * 8;            // lane*16B in shorts

    // stage(buf, step): each wave DMAs its quarter (4KB K + 4KB V) = 8 instrs
#define STAGE(BUF, S)                                                          \
    do {                                                                       \
      const unsigned short* kg_ = kb0 + (size_t)(S) * 8192 + w * 2048 + lo;    \
      const unsigned short* vg_ = vb0 + (size_t)(S) * 8192 + w * 2048 + lo;    \
      short* kl_ = &Klds[BUF][w * 2048];                                       \
      short* vl_ = &Vtlds[BUF][w * 2048];                                      \
      _Pragma("unroll")                                                        \
      for (int i_ = 0; i_ < 4; ++i_) dma16(kg_ + i_ * 512, kl_ + i_ * 512);    \
      _Pragma("unroll")                                                        \
      for (int i_ = 0; i_ < 4; ++i_) dma16(vg_ + i_ * 512, vl_ + i_ * 512);    \
    } while (0)

    // ---- prologue: stage s0 (and s0+1 into the other buffer) ----
    STAGE(s0 & 1, s0);
    if (s0 + 1 < s1) {
      STAGE((s0 + 1) & 1, s0 + 1);
      asm volatile("s_waitcnt vmcnt(8)" ::: "memory");   // s0's 8 done
    } else {
      asm volatile("s_waitcnt vmcnt(0)" ::: "memory");
    }
    __builtin_amdgcn_s_barrier();
    __builtin_amdgcn_sched_barrier(0);

    for (int s = s0; s < s1; ++s) {
      const int kt  = s * KB;
      const int cur = s & 1;
      const short* Kl = &Klds[cur][0];
      const short* Vl = &Vtlds[cur][0];
      const bool act = (kt <= q0 + w * 32 + 31);   // wave fully masked beyond

      short8 pa[2][2];
      if (act) {
        // ---- S^T = K*Q^T for both subtiles; each A-frag read used twice ----
        floatx4 st[2][4];
#pragma unroll
        for (int kf = 0; kf < 4; ++kf) {
          floatx4 c0 = (floatx4){0.f, 0.f, 0.f, 0.f};
          floatx4 c1 = (floatx4){0.f, 0.f, 0.f, 0.f};
#pragma unroll
          for (int kd = 0; kd < 4; ++kd) {
            short8 a = *(const short8*)(&Kl[((kf * 16 + l15) << 7) + ((kd * 32 + quad * 8) ^ xk)]);
            c0 = __builtin_amdgcn_mfma_f32_16x16x32_bf16(a, bq[0][kd], c0, 0, 0, 0);
            c1 = __builtin_amdgcn_mfma_f32_16x16x32_bf16(a, bq[1][kd], c1, 0, 0, 0);
          }
          st[0][kf] = c0;
          st[1][kf] = c1;
        }

        // ---- causal mask (boundary subtiles only) ----
#pragma unroll
        for (int sub = 0; sub < 2; ++sub) {
          if (kt + 63 > q0 + w * 32 + sub * 16) {
#pragma unroll
            for (int kf = 0; kf < 4; ++kf)
#pragma unroll
              for (int r = 0; r < 4; ++r) {
                int key = kt + kf * 16 + quad * 4 + r;
                if (key > qg[sub]) st[sub][kf][r] = -1e30f;
              }
          }
        }

        // ---- online softmax + P roundtrip + rescale, per subtile ----
#pragma unroll
        for (int sub = 0; sub < 2; ++sub) {
          float mx = st[sub][0][0];
#pragma unroll
          for (int kf = 0; kf < 4; ++kf)
#pragma unroll
            for (int r = 0; r < 4; ++r) mx = fmaxf(mx, st[sub][kf][r]);
          mx = fmaxf(mx, __shfl_xor(mx, 16, 64));
          mx = fmaxf(mx, __shfl_xor(mx, 32, 64));
          const float m_new = fmaxf(m_run[sub], mx);
          const float alpha = EXP2F((m_run[sub] - m_new) * CSC);

          float p[4][4];
          float tsum = 0.f;
#pragma unroll
          for (int kf = 0; kf < 4; ++kf)
#pragma unroll
            for (int r = 0; r < 4; ++r) {
              p[kf][r] = EXP2F((st[sub][kf][r] - m_new) * CSC);
              tsum += p[kf][r];
            }
          tsum += __shfl_xor(tsum, 16, 64);
          tsum += __shfl_xor(tsum, 32, 64);
          l_run[sub] = l_run[sub] * alpha + tsum;
          m_run[sub] = m_new;

#pragma unroll
          for (int r = 0; r < 4; ++r) {
            const float ar = __shfl(alpha, quad * 4 + r, 64);
#pragma unroll
            for (int nc = 0; nc < 8; ++nc) acc[sub][nc][r] *= ar;
          }

          // P: C-layout -> A-layout; wave-private rows (in-order LDS per wave)
          short* pw = &Plds[(w * 16 + l15) * PT_STR];
#pragma unroll
          for (int kf = 0; kf < 4; ++kf) {
            uint2 u;
            u.x = cvtpk(p[kf][0], p[kf][1]);
            u.y = cvtpk(p[kf][2], p[kf][3]);
            *(uint2*)(&pw[kf * 16 + quad * 4]) = u;
          }
          __asm__ __volatile__("" ::: "memory");
          pa[sub][0] = *(const short8*)(&pw[quad * 8]);
          pa[sub][1] = *(const short8*)(&pw[32 + quad * 8]);
          __asm__ __volatile__("" ::: "memory");
        }

        // ---- O += P*V ; each B-frag read used by both subtiles ----
#pragma unroll
        for (int nc = 0; nc < 8; ++nc) {
          short8 bv0 = *(const short8*)(&Vl[((nc * 16 + l15) << 6) + ((quad * 8) ^ xk)]);
          short8 bv1 = *(const short8*)(&Vl[((nc * 16 + l15) << 6) + ((32 + quad * 8) ^ xk)]);
          acc[0][nc] = __builtin_amdgcn_mfma_f32_16x16x32_bf16(pa[0][0], bv0, acc[0][nc], 0, 0, 0);
          acc[0][nc] = __builtin_amdgcn_mfma_f32_16x16x32_bf16(pa[0][1], bv1, acc[0][nc], 0, 0, 0);
          acc[1][nc] = __builtin_amdgcn_mfma_f32_16x16x32_bf16(pa[1][0], bv0, acc[1][nc], 0, 0, 0);
          acc[1][nc] = __builtin_amdgcn_mfma_f32_16x16x32_bf16(pa[1][1], bv1, acc[1][nc], 0, 0, 0);
        }
      }

      // ---- pipeline advance: free buf[cur], stage s+2 into it, await s+1 ----
      asm volatile("s_waitcnt lgkmcnt(0)" ::: "memory");
      __builtin_amdgcn_s_barrier();               // all waves done reading buf[cur]
      __builtin_amdgcn_sched_barrier(0);
      if (s + 2 < s1) {
        STAGE(cur, s + 2);
        asm volatile("s_waitcnt vmcnt(8)" ::: "memory");   // s+1's 8 done
      } else if (s + 1 < s1) {
        asm volatile("s_waitcnt vmcnt(0)" ::: "memory");
      }
      __builtin_amdgcn_s_barrier();               // buf[(s+1)&1] visible to all
      __builtin_amdgcn_sched_barrier(0);
    }
#undef STAGE

    // ---- partial epilogue: unnormalized O + (m,l) ----
    const int slot = ((b << 5) | q) * 4 + j;
    float* po = pO + (size_t)slot * 16384;
#pragma unroll
    for (int sub = 0; sub < 2; ++sub) {
#pragma unroll
      for (int r = 0; r < 4; ++r) {
        const int qrow = w * 32 + sub * 16 + quad * 4 + r;
        float* op = po + qrow * D_K + l15;
#pragma unroll
        for (int nc = 0; nc < 8; ++nc) op[nc * 16] = acc[sub][nc][r];
      }
      if (quad == 0) {
        const int qrow = w * 32 + sub * 16 + l15;
        ml[(size_t)slot * 256 + qrow * 2]     = m_run[sub];
        ml[(size_t)slot * 256 + qrow * 2 + 1] = l_run[sub];
      }
    }
  }
}

// ======================= combine kernel =======================
// 256 blocks (one per (b, 128-q tile)); rescale-and-sum up to 4 partials.

__global__ __launch_bounds__(256)
void attn_combine(const float* __restrict__ ml, const float* __restrict__ pO,
                  float* __restrict__ O) {
  const int t = blockIdx.x;           // 0..255 = b*32 + q
  const int b = t >> 5;
  const int q = t & 31;
  const int ncb = (2 * q + 17) >> 4;  // chunks for this tile (1..4)
  const float CSC = 0.12752041f;

  const int tid = threadIdx.x;
  const int ql  = tid >> 1;           // 0..127
  const int dh  = (tid & 1) * 64;     // d-span of 64 floats

  float m[4], l[4], wgt[4];
  float M = -1e30f;
#pragma unroll
  for (int jj = 0; jj < 4; ++jj) {
    if (jj < ncb) {
      const int slot = t * 4 + jj;
      m[jj] = ml[(size_t)slot * 256 + ql * 2];
      l[jj] = ml[(size_t)slot * 256 + ql * 2 + 1];
      M = fmaxf(M, m[jj]);
    }
  }
  float L = 0.f;
#pragma unroll
  for (int jj = 0; jj < 4; ++jj)
    if (jj < ncb) { wgt[jj] = EXP2F((m[jj] - M) * CSC); L += wgt[jj] * l[jj]; }
  const float inv = 1.0f / L;

  float4 out[16];
#pragma unroll
  for (int v = 0; v < 16; ++v) out[v] = make_float4(0.f, 0.f, 0.f, 0.f);
#pragma unroll
  for (int jj = 0; jj < 4; ++jj) {
    if (jj < ncb) {
      const float* src = pO + (size_t)(t * 4 + jj) * 16384 + ql * D_K + dh;
      const float wj = wgt[jj];
#pragma unroll
      for (int v = 0; v < 16; ++v) {
        float4 f = *(const float4*)(src + v * 4);
        out[v].x += wj * f.x;  out[v].y += wj * f.y;
        out[v].z += wj * f.z;  out[v].w += wj * f.w;
      }
    }
  }
  float* dst = O + ((size_t)(b * S_LEN) + q * 128 + ql) * D_K + dh;
#pragma unroll
  for (int v = 0; v < 16; ++v) {
    *(float4*)(dst + v * 4) = make_float4(out[v].x * inv, out[v].y * inv,
                                          out[v].z * inv, out[v].w * inv);
  }
}

// ======================= fallback (known-good, ws-too-small path) =======================

#define KT_STR 136
#define VT_STR 72

__global__ __launch_bounds__(256, 2)
void attn_fwd_fb(const float* __restrict__ Q, const float* __restrict__ K,
                 const float* __restrict__ V, float* __restrict__ O) {
  __shared__ __align__(16) short Klds[KB * KT_STR];
  __shared__ __align__(16) short Vtlds[D_K * VT_STR];
  __shared__ __align__(16) short Plds[4 * 16 * PT_STR];

  const int tid  = threadIdx.x;
  const int lane = tid & 63;
  const int w    = tid >> 6;
  const int l15  = lane & 15;
  const int quad = lane >> 4;

  const int bid = blockIdx.x;
  const int b   = bid & 7;
  const int qi  = 63 - (bid >> 3);
  const int q0  = qi * 64;

  const float CSC = 0.12752041f;

  const int    qg   = q0 + w * 16 + l15;
  const float* qrow = Q + (size_t)(b * S_LEN + qg) * D_K + quad * 8;
  short8 bq[4];
#pragma unroll
  for (int kd = 0; kd < 4; ++kd) {
    float4 f0 = *(const float4*)(qrow + kd * 32);
    float4 f1 = *(const float4*)(qrow + kd * 32 + 4);
    union { short8 s; unsigned u[4]; } t;
    t.u[0] = bfpack2(f0.x, f0.y);
    t.u[1] = bfpack2(f0.z, f0.w);
    t.u[2] = bfpack2(f1.x, f1.y);
    t.u[3] = bfpack2(f1.z, f1.w);
    bq[kd] = t.s;
  }

  floatx4 acc[8];
#pragma unroll
  for (int nc = 0; nc < 8; ++nc) acc[nc] = (floatx4){0.f, 0.f, 0.f, 0.f};
  float m_run = -1e30f, l_run = 0.f;

  const int d4 = tid & 31;
  const int kq = tid >> 5;
  const int nsteps = qi + 1;

  for (int s = 0; s < nsteps; ++s) {
    const int kt = s * KB;
#pragma unroll
    for (int r2 = 0; r2 < 2; ++r2) {
      const int row = r2 * 32 + kq * 4;
      const float* kp = K + (size_t)(b * S_LEN + kt + row) * D_K + d4 * 4;
      const float* vp = V + (size_t)(b * S_LEN + kt + row) * D_K + d4 * 4;
      float4 fk[4], fv[4];
#pragma unroll
      for (int i = 0; i < 4; ++i) {
        fk[i] = *(const float4*)(kp + i * D_K);
        fv[i] = *(const float4*)(vp + i * D_K);
      }
#pragma unroll
      for (int i = 0; i < 4; ++i) {
        uint2 u;
        u.x = bfpack2(fk[i].x, fk[i].y);
        u.y = bfpack2(fk[i].z, fk[i].w);
        *(uint2*)(&Klds[(row + i) * KT_STR + d4 * 4]) = u;
      }
#pragma unroll
      for (int c = 0; c < 4; ++c) {
        float e0 = ((const float*)&fv[0])[c];
        float e1 = ((const float*)&fv[1])[c];
        float e2 = ((const float*)&fv[2])[c];
        float e3 = ((const float*)&fv[3])[c];
        uint2 u;
        u.x = bfpack2(e0, e1);
        u.y = bfpack2(e2, e3);
        *(uint2*)(&Vtlds[(d4 * 4 + c) * VT_STR + row]) = u;
      }
    }
    __syncthreads();

    floatx4 st[4];
#pragma unroll
    for (int kf = 0; kf < 4; ++kf) {
      floatx4 cc = (floatx4){0.f, 0.f, 0.f, 0.f};
#pragma unroll
      for (int kd = 0; kd < 4; ++kd) {
        short8 a = *(const short8*)(&Klds[(kf * 16 + l15) * KT_STR + kd * 32 + quad * 8]);
        cc = __builtin_amdgcn_mfma_f32_16x16x32_bf16(a, bq[kd], cc, 0, 0, 0);
      }
      st[kf] = cc;
    }

    if (s == nsteps - 1) {
#pragma unroll
      for (int kf = 0; kf < 4; ++kf)
#pragma unroll
        for (int rr = 0; rr < 4; ++rr) {
          int key = kt + kf * 16 + quad * 4 + rr;
          if (key > qg) st[kf][rr] = -1e30f;
        }
    }

    float mx = st[0][0];
#pragma unroll
    for (int kf = 0; kf < 4; ++kf)
#pragma unroll
      for (int rr = 0; rr < 4; ++rr) mx = fmaxf(mx, st[kf][rr]);
    mx = fmaxf(mx, __shfl_xor(mx, 16, 64));
    mx = fmaxf(mx, __shfl_xor(mx, 32, 64));
    const float m_new = fmaxf(m_run, mx);
    const float alpha = EXP2F((m_run - m_new) * CSC);

    float p[4][4];
    float tsum = 0.f;
#pragma unroll
    for (int kf = 0; kf < 4; ++kf)
#pragma unroll
      for (int rr = 0; rr < 4; ++rr) {
        p[kf][rr] = EXP2F((st[kf][rr] - m_new) * CSC);
        tsum += p[kf][rr];
      }
    tsum += __shfl_xor(tsum, 16, 64);
    tsum += __shfl_xor(tsum, 32, 64);
    l_run = l_run * alpha + tsum;
    m_run = m_new;

#pragma unroll
    for (int rr = 0; rr < 4; ++rr) {
      const float ar = __shfl(alpha, quad * 4 + rr, 64);
#pragma unroll
      for (int nc = 0; nc < 8; ++nc) acc[nc][rr] *= ar;
    }

    short* pw = &Plds[(w * 16 + l15) * PT_STR];
#pragma unroll
    for (int kf = 0; kf < 4; ++kf) {
      uint2 u;
      u.x = bfpack2(p[kf][0], p[kf][1]);
      u.y = bfpack2(p[kf][2], p[kf][3]);
      *(uint2*)(&pw[kf * 16 + quad * 4]) = u;
    }
    __asm__ __volatile__("" ::: "memory");
    short8 pa0 = *(const short8*)(&pw[quad * 8]);
    short8 pa1 = *(const short8*)(&pw[32 + quad * 8]);

#pragma unroll
    for (int nc = 0; nc < 8; ++nc) {
      short8 bv0 = *(const short8*)(&Vtlds[(nc * 16 + l15) * VT_STR + quad * 8]);
      acc[nc] = __builtin_amdgcn_mfma_f32_16x16x32_bf16(pa0, bv0, acc[nc], 0, 0, 0);
      short8 bv1 = *(const short8*)(&Vtlds[(nc * 16 + l15) * VT_STR + 32 + quad * 8]);
      acc[nc] = __builtin_amdgcn_mfma_f32_16x16x32_bf16(pa1, bv1, acc[nc], 0, 0, 0);
    }
    __syncthreads();
  }

#pragma unroll
  for (int rr = 0; rr < 4; ++rr) {
    const float lr  = __shfl(l_run, quad * 4 + rr, 64);
    const float inv = 1.0f / lr;
    const int qout  = q0 + w * 16 + quad * 4 + rr;
    float* op = O + (size_t)(b * S_LEN + qout) * D_K + l15;
#pragma unroll
    for (int nc = 0; nc < 8; ++nc) op[nc * 16] = acc[nc][rr] * inv;
  }
}

// ======================= launch =======================

extern "C" void kernel_launch(void* const* d_in, const int* in_sizes, int n_in,
                              void* d_out, int out_size, void* d_ws, size_t ws_size,
                              hipStream_t stream) {
  const float* Q = (const float*)d_in[0];
  const float* K = (const float*)d_in[1];
  const float* V = (const float*)d_in[2];
  float* O = (float*)d_out;

  const size_t elems = (size_t)B_SZ * S_LEN * D_K;   // 4.19M

  // ws layout (bytes):
  //   0        : counter (int)
  //   256      : ml      [1024 slots][128 q][m,l]   = 1,048,576
  //   1,048,832: partO   [1024 slots][128][128]f32  = 67,108,864
  //   68,157,696: Kb tile-images bf16               =  8,388,608
  //   76,546,304: Vt tile-images bf16               =  8,388,608
  const size_t off_ml = 256;
  const size_t off_po = off_ml + 1024ull * 256 * 4;
  const size_t off_kb = off_po + 1024ull * 16384 * 4;
  const size_t off_vt = off_kb + elems * 2;
  const size_t need   = off_vt + elems * 2;

  if (ws_size >= need) {
    char* ws = (char*)d_ws;
    int*            cnt = (int*)ws;
    float*          mlp = (float*)(ws + off_ml);
    float*          po  = (float*)(ws + off_po);
    unsigned short* Kbp = (unsigned short*)(ws + off_kb);
    unsigned short* Vtp = (unsigned short*)(ws + off_vt);

    zero_cnt<<<dim3(1), dim3(1), 0, stream>>>(cnt);
    prep<<<dim3(B_SZ * 64), dim3(256), 0, stream>>>(K, V, Kbp, Vtp);
    attn_worker<<<dim3(512), dim3(256), 0, stream>>>(Q, Kbp, Vtp, cnt, mlp, po);
    attn_combine<<<dim3(256), dim3(256), 0, stream>>>(mlp, po, O);
  } else {
    attn_fwd_fb<<<dim3(512), dim3(256), 0, stream>>>(Q, K, V, O);
  }
}

// Round 7
// 181.292 us; speedup vs baseline: 1.2975x; 1.0346x over previous
//
#include <hip/hip_runtime.h>

#define B_SZ   8
#define S_LEN  4096
#define D_K    128
#define KB     64      // keys per step
#define CH     16      // steps per chunk (split-K granularity)
#define NCHUNK 640     // 416 full 16-step chunks + 224 remainder chunks (128-q tiles)

#define PT_STR 72      // P-LDS row stride in shorts (R0-proven)

typedef short  short8  __attribute__((ext_vector_type(8)));
typedef float  floatx4 __attribute__((ext_vector_type(4)));

#define EXP2F(x) exp2f(x)

__device__ __forceinline__ unsigned bfround(float x) {
  unsigned u = __builtin_bit_cast(unsigned, x);
  return (u + 0x7fffu + ((u >> 16) & 1u)) >> 16;
}
__device__ __forceinline__ unsigned bfpack2(float a, float b) {
  return bfround(a) | (bfround(b) << 16);
}
// single-instruction RTNE pack (hot loop only; numerics validated R1-R4)
__device__ __forceinline__ unsigned cvtpk(float lo, float hi) {
  unsigned r;
  asm("v_cvt_pk_bf16_f32 %0, %1, %2" : "=v"(r) : "v"(lo), "v"(hi));
  return r;
}

// NOTE (R6 post-mortem): permlane16/32_swap-based reductions FAILED correctness
// (absmax 4.4) — the two-output self-swap reduction derivation does not match
// hardware. Reverted to the R0-proven __shfl_xor path. Do not reintroduce
// without an isolated µbench validation.

// Async global->LDS DMA, 16B per lane (wave writes 1024B contiguous LDS).
__device__ __forceinline__ void dma16(const void* g, const void* l) {
  __builtin_amdgcn_global_load_lds(
      (__attribute__((address_space(1))) unsigned int*)(unsigned long long)g,
      (__attribute__((address_space(3))) unsigned int*)(unsigned int)(unsigned long long)l,
      16, 0, 0);
}

// ======================= pre-pass: tile-image builder =======================
// One block per (b, step s): emits K and V^T as 16KB LDS tile IMAGES with the
// XOR bank-swizzle baked in (byte ^= ((row&7)<<4)), so the worker can DMA them
// linearly via global_load_lds (rule #21). Block 0 also zeroes the chunk
// counter (stream-ordered before the worker launch) — no zero_cnt kernel.

__global__ __launch_bounds__(256)
void prep(const float* __restrict__ K, const float* __restrict__ V,
          unsigned short* __restrict__ Kb, unsigned short* __restrict__ Vt,
          int* __restrict__ cnt) {
  __shared__ float tile[64][129];
  const int tid = threadIdx.x;
  const int bid = blockIdx.x;         // b*64 + s
  if (bid == 0 && tid == 0) *cnt = 0;
  const int b   = bid >> 6;
  const int s   = bid & 63;
  const int kt  = s * 64;

  // ---- K tile image ----
  {
    const int r  = tid >> 2;
    const int cq = tid & 3;
    const float* kp = K + (size_t)(b * S_LEN + kt + r) * D_K + cq * 32;
    unsigned short* kdst = Kb + (size_t)bid * 8192 + r * 128;
    const int xr = (r & 7) << 4;
#pragma unroll
    for (int jj = 0; jj < 4; ++jj) {
      float4 f0 = *(const float4*)(kp + jj * 8);
      float4 f1 = *(const float4*)(kp + jj * 8 + 4);
      uint4 u;
      u.x = bfpack2(f0.x, f0.y);
      u.y = bfpack2(f0.z, f0.w);
      u.z = bfpack2(f1.x, f1.y);
      u.w = bfpack2(f1.z, f1.w);
      const int o = (cq * 64 + jj * 16) ^ xr;
      *(uint4*)(kdst + (o >> 1)) = u;
    }
  }

  // ---- V tile: load to LDS f32 ----
  {
    const int k  = tid >> 2;
    const int cq = tid & 3;
    const float* vp = V + (size_t)(b * S_LEN + kt + k) * D_K + cq * 32;
#pragma unroll
    for (int i = 0; i < 8; ++i) {
      float4 f = *(const float4*)(vp + i * 4);
      tile[k][cq * 32 + i * 4]     = f.x;
      tile[k][cq * 32 + i * 4 + 1] = f.y;
      tile[k][cq * 32 + i * 4 + 2] = f.z;
      tile[k][cq * 32 + i * 4 + 3] = f.w;
    }
  }
  __syncthreads();

  // ---- V^T tile image (transposed + swizzled) ----
  {
    const int d = tid >> 1;
    const int h = tid & 1;
    unsigned short* vdst = Vt + (size_t)bid * 8192 + d * 64;
    const int xr = (d & 7) << 4;
#pragma unroll
    for (int jj = 0; jj < 4; ++jj) {
      const int k0 = h * 32 + jj * 8;
      uint4 u;
      u.x = bfpack2(tile[k0 + 0][d], tile[k0 + 1][d]);
      u.y = bfpack2(tile[k0 + 2][d], tile[k0 + 3][d]);
      u.z = bfpack2(tile[k0 + 4][d], tile[k0 + 5][d]);
      u.w = bfpack2(tile[k0 + 6][d], tile[k0 + 7][d]);
      const int o = (h * 64 + jj * 16) ^ xr;
      *(uint4*)(vdst + (o >> 1)) = u;
    }
  }
}

// ======================= worker kernel =======================
// R4 skeleton (4 waves, 128-q tile, DMA double-buffer pipeline, counted
// vmcnt(8), raw s_barrier) + R7 safe subset: grow-guarded rescale
// (R1/R2-validated), setprio around MFMA clusters (T5), fused counter-zero.
// Reductions: __shfl_xor (R0-proven). Permlane path removed (R6 failure).

__global__ __launch_bounds__(256, 2)
void attn_worker(const float* __restrict__ Q, const unsigned short* __restrict__ Kb,
                 const unsigned short* __restrict__ Vt, int* __restrict__ cnt,
                 float* __restrict__ ml, float* __restrict__ pO) {
  __shared__ __align__(16) short Klds[2][8192];          // 2 x 16KB
  __shared__ __align__(16) short Vtlds[2][8192];         // 2 x 16KB
  __shared__ __align__(16) short Plds[4 * 16 * PT_STR];  // 9216B
  __shared__ int s_chunk;

  const int tid  = threadIdx.x;
  const int lane = tid & 63;
  const int w    = tid >> 6;        // wave 0..3
  const int l15  = lane & 15;
  const int quad = lane >> 4;
  const int xk   = (l15 & 7) << 3;  // short-index XOR for swizzled reads

  const float CSC = 0.12752041f;    // log2(e)/sqrt(128)

  for (;;) {
    if (tid == 0) s_chunk = atomicAdd(cnt, 1);
    __syncthreads();
    const int c = s_chunk;
    if (c >= NCHUNK) break;

    // ---- decode: 416 full chunks (desc q), then 224 remainders (desc size) ----
    int b, q, j;
    if (c < 416) {
      const int r = c >> 3;  b = c & 7;
      if      (r <  4) { q = 31;              j = r;         }
      else if (r < 28) { q = 30 - (r-4)/3;    j = (r-4)%3;   }
      else if (r < 44) { q = 22 - (r-28)/2;   j = (r-28)%2;  }
      else             { q = 14 - (r-44);     j = 0;         }
    } else {
      const int rc = c - 416;
      const int g  = rc >> 5;          // 0..6, remainder size 14-2g
      const int t  = rc & 31;
      b = t & 7;
      q = (6 - g) + 8 * (3 - (t >> 3));
      j = (q + 1) >> 3;                // = floor((2q+2)/16)
    }

    const int q0 = q * 128;
    const int s0 = j * CH;
    const int s1 = min(s0 + CH, 2 * q + 2);

    // ---- Q fragments for 2 subtiles (B-operand: n=l15=query, k=quad*8+i=d) ----
    short8 bq[2][4];
    int qg[2];
#pragma unroll
    for (int sub = 0; sub < 2; ++sub) {
      qg[sub] = q0 + w * 32 + sub * 16 + l15;
      const float* qrow = Q + (size_t)(b * S_LEN + qg[sub]) * D_K + quad * 8;
#pragma unroll
      for (int kd = 0; kd < 4; ++kd) {
        float4 f0 = *(const float4*)(qrow + kd * 32);
        float4 f1 = *(const float4*)(qrow + kd * 32 + 4);
        union { short8 s; unsigned u[4]; } t;
        t.u[0] = bfpack2(f0.x, f0.y);
        t.u[1] = bfpack2(f0.z, f0.w);
        t.u[2] = bfpack2(f1.x, f1.y);
        t.u[3] = bfpack2(f1.z, f1.w);
        bq[sub][kd] = t.s;
      }
    }

    floatx4 acc[2][8];
#pragma unroll
    for (int sub = 0; sub < 2; ++sub)
#pragma unroll
      for (int nc = 0; nc < 8; ++nc) acc[sub][nc] = (floatx4){0.f, 0.f, 0.f, 0.f};
    float m_run[2] = {-1e30f, -1e30f}, l_run[2] = {0.f, 0.f};

    const unsigned short* kb0 = Kb + (size_t)b * 64 * 8192;   // tile images
    const unsigned short* vb0 = Vt + (size_t)b * 64 * 8192;
    const int lo = lane * 8;            // lane*16B in shorts

    // stage(buf, step): each wave DMAs its quarter (4KB K + 4KB V) = 8 instrs
#define STAGE(BUF, S)                                                          \
    do {                                                                       \
      const unsigned short* kg_ = kb0 + (size_t)(S) * 8192 + w * 2048 + lo;    \
      const unsigned short* vg_ = vb0 + (size_t)(S) * 8192 + w * 2048 + lo;    \
      short* kl_ = &Klds[BUF][w * 2048];                                       \
      short* vl_ = &Vtlds[BUF][w * 2048];                                      \
      _Pragma("unroll")                                                        \
      for (int i_ = 0; i_ < 4; ++i_) dma16(kg_ + i_ * 512, kl_ + i_ * 512);    \
      _Pragma("unroll")                                                        \
      for (int i_ = 0; i_ < 4; ++i_) dma16(vg_ + i_ * 512, vl_ + i_ * 512);    \
    } while (0)

    // ---- prologue: stage s0 (and s0+1 into the other buffer) ----
    STAGE(s0 & 1, s0);
    if (s0 + 1 < s1) {
      STAGE((s0 + 1) & 1, s0 + 1);
      asm volatile("s_waitcnt vmcnt(8)" ::: "memory");   // s0's 8 done
    } else {
      asm volatile("s_waitcnt vmcnt(0)" ::: "memory");
    }
    __builtin_amdgcn_s_barrier();
    __builtin_amdgcn_sched_barrier(0);

    for (int s = s0; s < s1; ++s) {
      const int kt  = s * KB;
      const int cur = s & 1;
      const short* Kl = &Klds[cur][0];
      const short* Vl = &Vtlds[cur][0];
      const bool act = (kt <= q0 + w * 32 + 31);   // wave fully masked beyond

      short8 pa[2][2];
      if (act) {
        // ---- S^T = K*Q^T for both subtiles; each A-frag read used twice ----
        floatx4 st[2][4];
        __builtin_amdgcn_s_setprio(1);
#pragma unroll
        for (int kf = 0; kf < 4; ++kf) {
          floatx4 c0 = (floatx4){0.f, 0.f, 0.f, 0.f};
          floatx4 c1 = (floatx4){0.f, 0.f, 0.f, 0.f};
#pragma unroll
          for (int kd = 0; kd < 4; ++kd) {
            short8 a = *(const short8*)(&Kl[((kf * 16 + l15) << 7) + ((kd * 32 + quad * 8) ^ xk)]);
            c0 = __builtin_amdgcn_mfma_f32_16x16x32_bf16(a, bq[0][kd], c0, 0, 0, 0);
            c1 = __builtin_amdgcn_mfma_f32_16x16x32_bf16(a, bq[1][kd], c1, 0, 0, 0);
          }
          st[0][kf] = c0;
          st[1][kf] = c1;
        }
        __builtin_amdgcn_s_setprio(0);

        // ---- causal mask (boundary subtiles only) ----
#pragma unroll
        for (int sub = 0; sub < 2; ++sub) {
          if (kt + 63 > q0 + w * 32 + sub * 16) {
#pragma unroll
            for (int kf = 0; kf < 4; ++kf)
#pragma unroll
              for (int r = 0; r < 4; ++r) {
                int key = kt + kf * 16 + quad * 4 + r;
                if (key > qg[sub]) st[sub][kf][r] = -1e30f;
              }
          }
        }

        // ---- online softmax + P roundtrip + (guarded) rescale, per subtile ----
#pragma unroll
        for (int sub = 0; sub < 2; ++sub) {
          float mx = st[sub][0][0];
#pragma unroll
          for (int kf = 0; kf < 4; ++kf)
#pragma unroll
            for (int r = 0; r < 4; ++r) mx = fmaxf(mx, st[sub][kf][r]);
          mx = fmaxf(mx, __shfl_xor(mx, 16, 64));
          mx = fmaxf(mx, __shfl_xor(mx, 32, 64));
          const float m_new = fmaxf(m_run[sub], mx);
          const bool  grow  = __any(m_new > m_run[sub]);

          float p[4][4];
          float tsum = 0.f;
#pragma unroll
          for (int kf = 0; kf < 4; ++kf)
#pragma unroll
            for (int r = 0; r < 4; ++r) {
              p[kf][r] = EXP2F((st[sub][kf][r] - m_new) * CSC);
              tsum += p[kf][r];
            }
          tsum += __shfl_xor(tsum, 16, 64);
          tsum += __shfl_xor(tsum, 32, 64);

          if (grow) {
            const float alpha = EXP2F((m_run[sub] - m_new) * CSC);
            l_run[sub] = l_run[sub] * alpha + tsum;
#pragma unroll
            for (int r = 0; r < 4; ++r) {
              const float ar = __shfl(alpha, quad * 4 + r, 64);
#pragma unroll
              for (int nc = 0; nc < 8; ++nc) acc[sub][nc][r] *= ar;
            }
          } else {
            l_run[sub] = l_run[sub] + tsum;   // m_new == m_run for every query
          }
          m_run[sub] = m_new;

          // P: C-layout -> A-layout; wave-private rows (in-order LDS per wave)
          short* pw = &Plds[(w * 16 + l15) * PT_STR];
#pragma unroll
          for (int kf = 0; kf < 4; ++kf) {
            uint2 u;
            u.x = cvtpk(p[kf][0], p[kf][1]);
            u.y = cvtpk(p[kf][2], p[kf][3]);
            *(uint2*)(&pw[kf * 16 + quad * 4]) = u;
          }
          __asm__ __volatile__("" ::: "memory");
          pa[sub][0] = *(const short8*)(&pw[quad * 8]);
          pa[sub][1] = *(const short8*)(&pw[32 + quad * 8]);
          __asm__ __volatile__("" ::: "memory");
        }

        // ---- O += P*V ; each B-frag read used by both subtiles ----
        __builtin_amdgcn_s_setprio(1);
#pragma unroll
        for (int nc = 0; nc < 8; ++nc) {
          short8 bv0 = *(const short8*)(&Vl[((nc * 16 + l15) << 6) + ((quad * 8) ^ xk)]);
          short8 bv1 = *(const short8*)(&Vl[((nc * 16 + l15) << 6) + ((32 + quad * 8) ^ xk)]);
          acc[0][nc] = __builtin_amdgcn_mfma_f32_16x16x32_bf16(pa[0][0], bv0, acc[0][nc], 0, 0, 0);
          acc[0][nc] = __builtin_amdgcn_mfma_f32_16x16x32_bf16(pa[0][1], bv1, acc[0][nc], 0, 0, 0);
          acc[1][nc] = __builtin_amdgcn_mfma_f32_16x16x32_bf16(pa[1][0], bv0, acc[1][nc], 0, 0, 0);
          acc[1][nc] = __builtin_amdgcn_mfma_f32_16x16x32_bf16(pa[1][1], bv1, acc[1][nc], 0, 0, 0);
        }
        __builtin_amdgcn_s_setprio(0);
      }

      // ---- pipeline advance: free buf[cur], stage s+2 into it, await s+1 ----
      asm volatile("s_waitcnt lgkmcnt(0)" ::: "memory");
      __builtin_amdgcn_s_barrier();               // all waves done reading buf[cur]
      __builtin_amdgcn_sched_barrier(0);
      if (s + 2 < s1) {
        STAGE(cur, s + 2);
        asm volatile("s_waitcnt vmcnt(8)" ::: "memory");   // s+1's 8 done
      } else if (s + 1 < s1) {
        asm volatile("s_waitcnt vmcnt(0)" ::: "memory");
      }
      __builtin_amdgcn_s_barrier();               // buf[(s+1)&1] visible to all
      __builtin_amdgcn_sched_barrier(0);
    }
#undef STAGE

    // ---- partial epilogue: unnormalized O + (m,l) ----
    const int slot = ((b << 5) | q) * 4 + j;
    float* po = pO + (size_t)slot * 16384;
#pragma unroll
    for (int sub = 0; sub < 2; ++sub) {
#pragma unroll
      for (int r = 0; r < 4; ++r) {
        const int qrow = w * 32 + sub * 16 + quad * 4 + r;
        float* op = po + qrow * D_K + l15;
#pragma unroll
        for (int nc = 0; nc < 8; ++nc) op[nc * 16] = acc[sub][nc][r];
      }
      if (quad == 0) {
        const int qrow = w * 32 + sub * 16 + l15;
        ml[(size_t)slot * 256 + qrow * 2]     = m_run[sub];
        ml[(size_t)slot * 256 + qrow * 2 + 1] = l_run[sub];
      }
    }
  }
}

// ======================= combine kernel =======================
// 256 blocks (one per (b, 128-q tile)); rescale-and-sum up to 4 partials.

__global__ __launch_bounds__(256)
void attn_combine(const float* __restrict__ ml, const float* __restrict__ pO,
                  float* __restrict__ O) {
  const int t = blockIdx.x;           // 0..255 = b*32 + q
  const int b = t >> 5;
  const int q = t & 31;
  const int ncb = (2 * q + 17) >> 4;  // chunks for this tile (1..4)
  const float CSC = 0.12752041f;

  const int tid = threadIdx.x;
  const int ql  = tid >> 1;           // 0..127
  const int dh  = (tid & 1) * 64;     // d-span of 64 floats

  float m[4], l[4], wgt[4];
  float M = -1e30f;
#pragma unroll
  for (int jj = 0; jj < 4; ++jj) {
    if (jj < ncb) {
      const int slot = t * 4 + jj;
      m[jj] = ml[(size_t)slot * 256 + ql * 2];
      l[jj] = ml[(size_t)slot * 256 + ql * 2 + 1];
      M = fmaxf(M, m[jj]);
    }
  }
  float L = 0.f;
#pragma unroll
  for (int jj = 0; jj < 4; ++jj)
    if (jj < ncb) { wgt[jj] = EXP2F((m[jj] - M) * CSC); L += wgt[jj] * l[jj]; }
  const float inv = 1.0f / L;

  float4 out[16];
#pragma unroll
  for (int v = 0; v < 16; ++v) out[v] = make_float4(0.f, 0.f, 0.f, 0.f);
#pragma unroll
  for (int jj = 0; jj < 4; ++jj) {
    if (jj < ncb) {
      const float* src = pO + (size_t)(t * 4 + jj) * 16384 + ql * D_K + dh;
      const float wj = wgt[jj];
#pragma unroll
      for (int v = 0; v < 16; ++v) {
        float4 f = *(const float4*)(src + v * 4);
        out[v].x += wj * f.x;  out[v].y += wj * f.y;
        out[v].z += wj * f.z;  out[v].w += wj * f.w;
      }
    }
  }
  float* dst = O + ((size_t)(b * S_LEN) + q * 128 + ql) * D_K + dh;
#pragma unroll
  for (int v = 0; v < 16; ++v) {
    *(float4*)(dst + v * 4) = make_float4(out[v].x * inv, out[v].y * inv,
                                          out[v].z * inv, out[v].w * inv);
  }
}

// ======================= fallback (known-good, ws-too-small path) =======================

#define KT_STR 136
#define VT_STR 72

__global__ __launch_bounds__(256, 2)
void attn_fwd_fb(const float* __restrict__ Q, const float* __restrict__ K,
                 const float* __restrict__ V, float* __restrict__ O) {
  __shared__ __align__(16) short Klds[KB * KT_STR];
  __shared__ __align__(16) short Vtlds[D_K * VT_STR];
  __shared__ __align__(16) short Plds[4 * 16 * PT_STR];

  const int tid  = threadIdx.x;
  const int lane = tid & 63;
  const int w    = tid >> 6;
  const int l15  = lane & 15;
  const int quad = lane >> 4;

  const int bid = blockIdx.x;
  const int b   = bid & 7;
  const int qi  = 63 - (bid >> 3);
  const int q0  = qi * 64;

  const float CSC = 0.12752041f;

  const int    qg   = q0 + w * 16 + l15;
  const float* qrow = Q + (size_t)(b * S_LEN + qg) * D_K + quad * 8;
  short8 bq[4];
#pragma unroll
  for (int kd = 0; kd < 4; ++kd) {
    float4 f0 = *(const float4*)(qrow + kd * 32);
    float4 f1 = *(const float4*)(qrow + kd * 32 + 4);
    union { short8 s; unsigned u[4]; } t;
    t.u[0] = bfpack2(f0.x, f0.y);
    t.u[1] = bfpack2(f0.z, f0.w);
    t.u[2] = bfpack2(f1.x, f1.y);
    t.u[3] = bfpack2(f1.z, f1.w);
    bq[kd] = t.s;
  }

  floatx4 acc[8];
#pragma unroll
  for (int nc = 0; nc < 8; ++nc) acc[nc] = (floatx4){0.f, 0.f, 0.f, 0.f};
  float m_run = -1e30f, l_run = 0.f;

  const int d4 = tid & 31;
  const int kq = tid >> 5;
  const int nsteps = qi + 1;

  for (int s = 0; s < nsteps; ++s) {
    const int kt = s * KB;
#pragma unroll
    for (int r2 = 0; r2 < 2; ++r2) {
      const int row = r2 * 32 + kq * 4;
      const float* kp = K + (size_t)(b * S_LEN + kt + row) * D_K + d4 * 4;
      const float* vp = V + (size_t)(b * S_LEN + kt + row) * D_K + d4 * 4;
      float4 fk[4], fv[4];
#pragma unroll
      for (int i = 0; i < 4; ++i) {
        fk[i] = *(const float4*)(kp + i * D_K);
        fv[i] = *(const float4*)(vp + i * D_K);
      }
#pragma unroll
      for (int i = 0; i < 4; ++i) {
        uint2 u;
        u.x = bfpack2(fk[i].x, fk[i].y);
        u.y = bfpack2(fk[i].z, fk[i].w);
        *(uint2*)(&Klds[(row + i) * KT_STR + d4 * 4]) = u;
      }
#pragma unroll
      for (int c = 0; c < 4; ++c) {
        float e0 = ((const float*)&fv[0])[c];
        float e1 = ((const float*)&fv[1])[c];
        float e2 = ((const float*)&fv[2])[c];
        float e3 = ((const float*)&fv[3])[c];
        uint2 u;
        u.x = bfpack2(e0, e1);
        u.y = bfpack2(e2, e3);
        *(uint2*)(&Vtlds[(d4 * 4 + c) * VT_STR + row]) = u;
      }
    }
    __syncthreads();

    floatx4 st[4];
#pragma unroll
    for (int kf = 0; kf < 4; ++kf) {
      floatx4 cc = (floatx4){0.f, 0.f, 0.f, 0.f};
#pragma unroll
      for (int kd = 0; kd < 4; ++kd) {
        short8 a = *(const short8*)(&Klds[(kf * 16 + l15) * KT_STR + kd * 32 + quad * 8]);
        cc = __builtin_amdgcn_mfma_f32_16x16x32_bf16(a, bq[kd], cc, 0, 0, 0);
      }
      st[kf] = cc;
    }

    if (s == nsteps - 1) {
#pragma unroll
      for (int kf = 0; kf < 4; ++kf)
#pragma unroll
        for (int rr = 0; rr < 4; ++rr) {
          int key = kt + kf * 16 + quad * 4 + rr;
          if (key > qg) st[kf][rr] = -1e30f;
        }
    }

    float mx = st[0][0];
#pragma unroll
    for (int kf = 0; kf < 4; ++kf)
#pragma unroll
      for (int rr = 0; rr < 4; ++rr) mx = fmaxf(mx, st[kf][rr]);
    mx = fmaxf(mx, __shfl_xor(mx, 16, 64));
    mx = fmaxf(mx, __shfl_xor(mx, 32, 64));
    const float m_new = fmaxf(m_run, mx);
    const float alpha = EXP2F((m_run - m_new) * CSC);

    float p[4][4];
    float tsum = 0.f;
#pragma unroll
    for (int kf = 0; kf < 4; ++kf)
#pragma unroll
      for (int rr = 0; rr < 4; ++rr) {
        p[kf][rr] = EXP2F((st[kf][rr] - m_new) * CSC);
        tsum += p[kf][rr];
      }
    tsum += __shfl_xor(tsum, 16, 64);
    tsum += __shfl_xor(tsum, 32, 64);
    l_run = l_run * alpha + tsum;
    m_run = m_new;

#pragma unroll
    for (int rr = 0; rr < 4; ++rr) {
      const float ar = __shfl(alpha, quad * 4 + rr, 64);
#pragma unroll
      for (int nc = 0; nc < 8; ++nc) acc[nc][rr] *= ar;
    }

    short* pw = &Plds[(w * 16 + l15) * PT_STR];
#pragma unroll
    for (int kf = 0; kf < 4; ++kf) {
      uint2 u;
      u.x = bfpack2(p[kf][0], p[kf][1]);
      u.y = bfpack2(p[kf][2], p[kf][3]);
      *(uint2*)(&pw[kf * 16 + quad * 4]) = u;
    }
    __asm__ __volatile__("" ::: "memory");
    short8 pa0 = *(const short8*)(&pw[quad * 8]);
    short8 pa1 = *(const short8*)(&pw[32 + quad * 8]);

#pragma unroll
    for (int nc = 0; nc < 8; ++nc) {
      short8 bv0 = *(const short8*)(&Vtlds[(nc * 16 + l15) * VT_STR + quad * 8]);
      acc[nc] = __builtin_amdgcn_mfma_f32_16x16x32_bf16(pa0, bv0, acc[nc], 0, 0, 0);
      short8 bv1 = *(const short8*)(&Vtlds[(nc * 16 + l15) * VT_STR + 32 + quad * 8]);
      acc[nc] = __builtin_amdgcn_mfma_f32_16x16x32_bf16(pa1, bv1, acc[nc], 0, 0, 0);
    }
    __syncthreads();
  }

#pragma unroll
  for (int rr = 0; rr < 4; ++rr) {
    const float lr  = __shfl(l_run, quad * 4 + rr, 64);
    const float inv = 1.0f / lr;
    const int qout  = q0 + w * 16 + quad * 4 + rr;
    float* op = O + (size_t)(b * S_LEN + qout) * D_K + l15;
#pragma unroll
    for (int nc = 0; nc < 8; ++nc) op[nc * 16] = acc[nc][rr] * inv;
  }
}

// ======================= launch =======================

extern "C" void kernel_launch(void* const* d_in, const int* in_sizes, int n_in,
                              void* d_out, int out_size, void* d_ws, size_t ws_size,
                              hipStream_t stream) {
  const float* Q = (const float*)d_in[0];
  const float* K = (const float*)d_in[1];
  const float* V = (const float*)d_in[2];
  float* O = (float*)d_out;

  const size_t elems = (size_t)B_SZ * S_LEN * D_K;   // 4.19M

  // ws layout (bytes):
  //   0        : counter (int)
  //   256      : ml      [1024 slots][128 q][m,l]   = 1,048,576
  //   1,048,832: partO   [1024 slots][128][128]f32  = 67,108,864
  //   68,157,696: Kb tile-images bf16               =  8,388,608
  //   76,546,304: Vt tile-images bf16               =  8,388,608
  const size_t off_ml = 256;
  const size_t off_po = off_ml + 1024ull * 256 * 4;
  const size_t off_kb = off_po + 1024ull * 16384 * 4;
  const size_t off_vt = off_kb + elems * 2;
  const size_t need   = off_vt + elems * 2;

  if (ws_size >= need) {
    char* ws = (char*)d_ws;
    int*            cnt = (int*)ws;
    float*          mlp = (float*)(ws + off_ml);
    float*          po  = (float*)(ws + off_po);
    unsigned short* Kbp = (unsigned short*)(ws + off_kb);
    unsigned short* Vtp = (unsigned short*)(ws + off_vt);

    prep<<<dim3(B_SZ * 64), dim3(256), 0, stream>>>(K, V, Kbp, Vtp, cnt);
    attn_worker<<<dim3(512), dim3(256), 0, stream>>>(Q, Kbp, Vtp, cnt, mlp, po);
    attn_combine<<<dim3(256), dim3(256), 0, stream>>>(mlp, po, O);
  } else {
    attn_fwd_fb<<<dim3(512), dim3(256), 0, stream>>>(Q, K, V, O);
  }
}